// Round 8
// baseline (1694.362 us; speedup 1.0000x reference)
//
#include <hip/hip_runtime.h>
#include <hip/hip_bf16.h>

// Problem constants (B=4, S=4096, D=4096, r=4, COFF=2, HD=512)
#define D_DIM 4096
#define OD    1024          // COFF*HD combined projection width
#define M_TOT 16384         // B*S
#define N_TOT 2048          // 2*OD (kv/gate interleaved)
#define BM 256
#define BN 256
#define BK 64

#define GLOBAL_AS __attribute__((address_space(1)))
#define LDS_AS    __attribute__((address_space(3)))

typedef __attribute__((ext_vector_type(8)))  short          bf16x8;
typedef __attribute__((ext_vector_type(8)))  unsigned short u16x8;
typedef __attribute__((ext_vector_type(4)))  float          f32x4;
typedef __attribute__((ext_vector_type(16))) float          f32x16;

__device__ __forceinline__ unsigned short f2bf(float f) {
    unsigned int u = __float_as_uint(f);
    u = (u + 0x7fffu + ((u >> 16) & 1u)) >> 16;
    return (unsigned short)u;
}

__device__ __forceinline__ float sigm(float x) {
    return 1.0f / (1.0f + __expf(-x));
}

__device__ __forceinline__ void gload16(const void* g, void* l) {
    __builtin_amdgcn_global_load_lds((const GLOBAL_AS void*)g, (LDS_AS void*)l, 16, 0, 0);
}

// ---- prep: interleave wkv/wgate rows into combined bf16 weight [2048][4096]
__global__ void prep_weights(const float* __restrict__ wkv,
                             const float* __restrict__ wgate,
                             unsigned short* __restrict__ Wc) {
    int t  = blockIdx.x * 256 + threadIdx.x;
    int n  = t >> 9;
    int k8 = t & 511;
    const float* src = (n & 1) ? wgate : wkv;
    const float4* s4 = (const float4*)(src + (size_t)(n >> 1) * D_DIM + k8 * 8);
    float4 a = s4[0], b = s4[1];
    u16x8 o;
    o[0] = f2bf(a.x); o[1] = f2bf(a.y); o[2] = f2bf(a.z); o[3] = f2bf(a.w);
    o[4] = f2bf(b.x); o[5] = f2bf(b.y); o[6] = f2bf(b.z); o[7] = f2bf(b.w);
    *(u16x8*)(Wc + (size_t)n * D_DIM + k8 * 8) = o;
}

// ---- prep: x fp32 -> bf16
__global__ void prep_x(const float* __restrict__ x, unsigned short* __restrict__ xb) {
    size_t t = (size_t)blockIdx.x * 256 + threadIdx.x;
    const float4* s = (const float4*)(x + t * 8);
    float4 a = s[0], b = s[1];
    u16x8 o;
    o[0] = f2bf(a.x); o[1] = f2bf(a.y); o[2] = f2bf(a.z); o[3] = f2bf(a.w);
    o[4] = f2bf(b.x); o[5] = f2bf(b.y); o[6] = f2bf(b.z); o[7] = f2bf(b.w);
    *(u16x8*)(xb + t * 8) = o;
}

// ---- prep: ape mean over the 4 window positions
__global__ void prep_ape(const float* __restrict__ ape, float* __restrict__ am) {
    int t = blockIdx.x * 256 + threadIdx.x;
    if (t < OD)
        am[t] = 0.25f * (ape[t] + ape[OD + t] + ape[2 * OD + t] + ape[3 * OD + t]);
}

// =====================================================================
// 256x256 / BK=64 / 8-wave / 8-phase GEMM with mfma_32x32x16_bf16.
// Phase = one K16-step of the whole wave tile (4 m-blocks x 2 n-blocks):
// 6 ds_read_b128 + 8 MFMA, operands consumed IN-phase (no cross-phase
// regs -> no spill; 48 b128/iter vs r5's 96). Full-buffer double-buffer:
// ph1-4 read buf0 / ph5-8 read buf1; ph1 stages next buf1 tile, ph5
// stages next buf0 tile (each issued just after the barrier ending all
// reads of that buffer); vmcnt(0) before ph4-end / ph8-end barriers
// (loads issued 3 phases ~500cy earlier -> drain covered).
// C/D layout (32x32): col=lane&31, row=(reg&3)+8*(reg>>2)+4*(lane>>5);
// each reg-quad = one r=4 pooling window; gate via shfl_xor(.,1).
// =====================================================================
extern __shared__ __align__(16) unsigned short smem_u16[];

__global__ __launch_bounds__(512, 2)
void gemm_fused_8ph(const unsigned short* __restrict__ A,
                    const unsigned short* __restrict__ Wc,
                    const float* __restrict__ ape_mean,
                    float* __restrict__ out_pooled) {
    unsigned short* Asb[2] = {smem_u16,               smem_u16 + BM * BK};
    unsigned short* Bsb[2] = {smem_u16 + 2 * BM * BK, smem_u16 + 3 * BM * BK};

    const int tid  = threadIdx.x;
    const int lane = tid & 63;
    const int wave = tid >> 6;          // 8 waves: wm = wave>>2 (2), wn = wave&3 (4)
    const int wm   = wave >> 2;
    const int wn   = wave & 3;
    const int col  = lane & 31;         // 32x32 fragment column
    const int hi   = lane >> 5;         // k-half selector / row offset +4

    // XCD partition by m: xcd = bid&7 owns m-tiles [xcd*8, xcd*8+8), all 8 n-tiles.
    const int bid = blockIdx.x;
    const int j   = bid >> 3;
    const int m0  = ((bid & 7) * 8 + (j >> 3)) * BM;
    const int n0  = (j & 7) * BN;

    // staging: pre-swizzled source chunk (rule 21 both-sides; verified r3)
    const int sc8 = (lane & 7) ^ ((lane >> 3) & 7);
    const unsigned short* Ag = A  + (size_t)(m0 + wave * 8 + (lane >> 3)) * D_DIM + sc8 * 8;
    const unsigned short* Bg = Wc + (size_t)(n0 + (wave & 3) * 8 + (lane >> 3)) * D_DIM + sc8 * 8;
    const int bstripe = wave >> 2;      // waves 0-3: stripes {0,2}; 4-7: {1,3}

#define STAGE_A(buf, half, kofs)                                                   \
    do {                                                                           \
        gload16(Ag + (size_t)((half) * 64) * D_DIM + (kofs),                       \
                Asb[buf] + ((half) * 64 + wave * 8) * BK);                         \
        gload16(Ag + (size_t)((half) * 64 + 128) * D_DIM + (kofs),                 \
                Asb[buf] + ((half) * 64 + 128 + wave * 8) * BK);                   \
    } while (0)

#define STAGE_B(buf, qb, kofs)                                                     \
    do {                                                                           \
        const int r0_ = (qb) * 32 + bstripe * 64;                                  \
        const int r1_ = (qb) * 32 + (2 + bstripe) * 64;                            \
        gload16(Bg + (size_t)r0_ * D_DIM + (kofs),                                 \
                Bsb[buf] + (r0_ + (wave & 3) * 8) * BK);                           \
        gload16(Bg + (size_t)r1_ * D_DIM + (kofs),                                 \
                Bsb[buf] + (r1_ + (wave & 3) * 8) * BK);                           \
    } while (0)

#define STAGE_FULL(buf, kofs)                                                      \
    do {                                                                           \
        STAGE_A(buf, 0, kofs); STAGE_A(buf, 1, kofs);                              \
        STAGE_B(buf, 0, kofs); STAGE_B(buf, 1, kofs);                              \
    } while (0)

#define BAR() __builtin_amdgcn_s_barrier()
#define VMW0() asm volatile("s_waitcnt vmcnt(0)" ::: "memory")

// One phase: K16-step `kstep` of buffer `buf`. 6 ds_read_b128 + 8 MFMA.
// STAGECODE issues gloads (or nothing). VM=1 -> vmcnt(0) before end-BAR.
#define PHASE32(buf, kstep, STAGECODE, VM)                                         \
    do {                                                                           \
        bf16x8 av[4], bv[2];                                                       \
        _Pragma("unroll")                                                          \
        for (int mi = 0; mi < 4; ++mi) {                                           \
            const int row = wm * 128 + mi * 32 + col;                              \
            av[mi] = *(const bf16x8*)&Asb[buf][(row * BK + (kstep) * 16 +          \
                     hi * 8) ^ ((row & 7) << 3)];                                  \
        }                                                                          \
        _Pragma("unroll")                                                          \
        for (int ni = 0; ni < 2; ++ni) {                                           \
            const int rw = wn * 64 + ni * 32 + col;                                \
            bv[ni] = *(const bf16x8*)&Bsb[buf][(rw * BK + (kstep) * 16 +           \
                     hi * 8) ^ ((rw & 7) << 3)];                                   \
        }                                                                          \
        STAGECODE;                                                                 \
        BAR();                                                                     \
        __builtin_amdgcn_s_setprio(1);                                             \
        _Pragma("unroll")                                                          \
        for (int mi = 0; mi < 4; ++mi)                                             \
            _Pragma("unroll")                                                      \
            for (int ni = 0; ni < 2; ++ni)                                         \
                acc[mi][ni] = __builtin_amdgcn_mfma_f32_32x32x16_bf16(             \
                    av[mi], bv[ni], acc[mi][ni], 0, 0, 0);                         \
        __builtin_amdgcn_s_setprio(0);                                             \
        if (VM) VMW0();                                                            \
        BAR();                                                                     \
    } while (0)

    f32x16 acc[4][2];
#pragma unroll
    for (int i = 0; i < 4; ++i)
#pragma unroll
        for (int jj = 0; jj < 2; ++jj)
#pragma unroll
            for (int e = 0; e < 16; ++e) acc[i][jj][e] = 0.f;

    // prologue: stage tile 0 -> buf0; buf1 gets tile 1 in first iter's ph1
    STAGE_FULL(0, 0);
    VMW0();
    BAR();

    for (int kt2 = 0; kt2 < D_DIM; kt2 += 2 * BK) {
        const int kb1 = kt2 + BK;        // odd tile for buf1 (<= 4032, never wraps)
        const int kna = kt2 + 2 * BK;    // next even tile for buf0
        // ph1-4: read buf0; ph1 stages buf1 (all its readers are >= ph5)
        PHASE32(0, 0, STAGE_FULL(1, kb1), 0);
        PHASE32(0, 1, , 0);
        PHASE32(0, 2, , 0);
        PHASE32(0, 3, , 1);              // vmcnt(0): buf1 loads (issued ph1) done
        // ph5-8: read buf1; ph5 stages buf0 (readers are next iter's ph1-4)
        if (kna < D_DIM) {
            PHASE32(1, 0, STAGE_FULL(0, kna), 0);
        } else {
            PHASE32(1, 0, , 0);
        }
        PHASE32(1, 1, , 0);
        PHASE32(1, 2, , 0);
        PHASE32(1, 3, , 1);              // vmcnt(0): buf0 loads (issued ph5) done
    }
#undef STAGE_A
#undef STAGE_B
#undef STAGE_FULL
#undef PHASE32
#undef BAR
#undef VMW0

    // Epilogue (32x32 C/D layout): even cols = kv, odd = gate (adjacent lanes).
    // reg quad rq covers rows 8rq+4hi .. +3  == one r=4 pooling window.
    const bool is_kv = ((lane & 1) == 0);
#pragma unroll
    for (int mi = 0; mi < 4; ++mi) {
        const int wbase = (m0 + wm * 128 + mi * 32) >> 2;   // 8 windows per block
#pragma unroll
        for (int ni = 0; ni < 2; ++ni) {
            const f32x16 c = acc[mi][ni];
            const int obase = ((n0 + wn * 64 + ni * 32) >> 1) + (col >> 1);
#pragma unroll
            for (int rq = 0; rq < 4; ++rq) {
                float v0 = c[rq * 4 + 0], v1 = c[rq * 4 + 1];
                float v2 = c[rq * 4 + 2], v3 = c[rq * 4 + 3];
                float g0 = __shfl_xor(v0, 1);
                float g1 = __shfl_xor(v1, 1);
                float g2 = __shfl_xor(v2, 1);
                float g3 = __shfl_xor(v3, 1);
                if (is_kv) {
                    float s = v0 * sigm(g0) + v1 * sigm(g1) +
                              v2 * sigm(g2) + v3 * sigm(g3);
                    const int w = wbase + 2 * rq + hi;
                    out_pooled[(size_t)w * OD + obase] = 0.25f * s + ape_mean[obase];
                }
            }
        }
    }
}

// ---- fallback (ws too small for xb): fp32 A + reg staging + XOR swizzle (r3)
__global__ __launch_bounds__(256)
void gemm_fused_f32(const float* __restrict__ Aptr,
                    const unsigned short* __restrict__ Wc,
                    const float* __restrict__ ape_mean,
                    float* __restrict__ out_pooled) {
    __shared__ __align__(16) unsigned short As[128 * BK];
    __shared__ __align__(16) unsigned short Bs[128 * BK];
    const int tid  = threadIdx.x;
    const int lane = tid & 63;
    const int wave = tid >> 6;
    const int wr   = wave >> 1;
    const int wc   = wave & 1;
    const int n0   = blockIdx.x * 128;
    const int m0   = blockIdx.y * 128;
    const int h    = lane & 15;
    const int q    = lane >> 4;

    f32x4 acc[4][4];
    const f32x4 z = {0.f, 0.f, 0.f, 0.f};
#pragma unroll
    for (int i = 0; i < 4; ++i)
#pragma unroll
        for (int jj = 0; jj < 4; ++jj) acc[i][jj] = z;

    for (int kt = 0; kt < D_DIM; kt += BK) {
#pragma unroll
        for (int i = 0; i < 4; ++i) {
            int chunk = tid + i * 256;
            int row = chunk >> 3, c8 = chunk & 7;
            int dst = (row * BK + c8 * 8) ^ ((row & 7) << 3);
            const float4* s = (const float4*)(Aptr + (size_t)(m0 + row) * D_DIM + kt + c8 * 8);
            float4 a = s[0], b = s[1];
            u16x8 o;
            o[0] = f2bf(a.x); o[1] = f2bf(a.y); o[2] = f2bf(a.z); o[3] = f2bf(a.w);
            o[4] = f2bf(b.x); o[5] = f2bf(b.y); o[6] = f2bf(b.z); o[7] = f2bf(b.w);
            *(u16x8*)&As[dst] = o;
        }
#pragma unroll
        for (int i = 0; i < 4; ++i) {
            int chunk = tid + i * 256;
            int row = chunk >> 3, c8 = chunk & 7;
            int dst = (row * BK + c8 * 8) ^ ((row & 7) << 3);
            *(u16x8*)&Bs[dst] =
                *(const u16x8*)(Wc + (size_t)(n0 + row) * D_DIM + kt + c8 * 8);
        }
        __syncthreads();
#pragma unroll
        for (int ks = 0; ks < 2; ++ks) {
            const int kb = ks * 32 + q * 8;
            bf16x8 af[4], bfr[4];
#pragma unroll
            for (int am = 0; am < 4; ++am) {
                int row = wr * 64 + am * 16 + h;
                af[am] = *(const bf16x8*)&As[(row * BK + kb) ^ ((row & 7) << 3)];
            }
#pragma unroll
            for (int bn = 0; bn < 4; ++bn) {
                int row = wc * 64 + bn * 16 + h;
                bfr[bn] = *(const bf16x8*)&Bs[(row * BK + kb) ^ ((row & 7) << 3)];
            }
#pragma unroll
            for (int am = 0; am < 4; ++am)
#pragma unroll
                for (int bn = 0; bn < 4; ++bn)
                    acc[am][bn] = __builtin_amdgcn_mfma_f32_16x16x32_bf16(
                        af[am], bfr[bn], acc[am][bn], 0, 0, 0);
        }
        __syncthreads();
    }
    const bool is_kv = ((h & 1) == 0);
#pragma unroll
    for (int am = 0; am < 4; ++am) {
        const int mbase = m0 + wr * 64 + am * 16 + q * 4;
        const int wglob = mbase >> 2;
#pragma unroll
        for (int bn = 0; bn < 4; ++bn) {
            f32x4 kv = acc[am][bn];
            float g0 = __shfl_xor(kv[0], 1);
            float g1 = __shfl_xor(kv[1], 1);
            float g2 = __shfl_xor(kv[2], 1);
            float g3 = __shfl_xor(kv[3], 1);
            if (is_kv) {
                float s = kv[0] * sigm(g0) + kv[1] * sigm(g1) +
                          kv[2] * sigm(g2) + kv[3] * sigm(g3);
                int n = n0 + wc * 64 + bn * 16 + h;
                int o = n >> 1;
                out_pooled[(size_t)wglob * OD + o] = 0.25f * s + ape_mean[o];
            }
        }
    }
}

// ---- in-place RMSNorm over head_dim=512 per token (8192 tokens)
__global__ void rmsnorm_inplace(float* __restrict__ out, const float* __restrict__ nw) {
    int token = blockIdx.x * 4 + (threadIdx.x >> 6);
    int lane  = threadIdx.x & 63;
    float4* p = (float4*)(out + (size_t)token * 512);
    float4 v0 = p[lane * 2], v1 = p[lane * 2 + 1];
    float ss = v0.x * v0.x + v0.y * v0.y + v0.z * v0.z + v0.w * v0.w +
               v1.x * v1.x + v1.y * v1.y + v1.z * v1.z + v1.w * v1.w;
#pragma unroll
    for (int off = 32; off > 0; off >>= 1) ss += __shfl_xor(ss, off);
    float rs = rsqrtf(ss * (1.0f / 512.0f) + 1e-6f);
    const float4* w4 = (const float4*)nw;
    float4 w0 = w4[lane * 2], w1 = w4[lane * 2 + 1];
    float4 r0, r1;
    r0.x = v0.x * rs * w0.x; r0.y = v0.y * rs * w0.y;
    r0.z = v0.z * rs * w0.z; r0.w = v0.w * rs * w0.w;
    r1.x = v1.x * rs * w1.x; r1.y = v1.y * rs * w1.y;
    r1.z = v1.z * rs * w1.z; r1.w = v1.w * rs * w1.w;
    p[lane * 2]     = r0;
    p[lane * 2 + 1] = r1;
}

extern "C" void kernel_launch(void* const* d_in, const int* in_sizes, int n_in,
                              void* d_out, int out_size, void* d_ws, size_t ws_size,
                              hipStream_t stream) {
    const float* x     = (const float*)d_in[0];
    const float* wkv   = (const float*)d_in[1];
    const float* wgate = (const float*)d_in[2];
    const float* ape   = (const float*)d_in[3];
    const float* normw = (const float*)d_in[4];
    float* out = (float*)d_out;

    unsigned short* Wc  = (unsigned short*)d_ws;
    float* ape_mean     = (float*)((char*)d_ws + (size_t)16 * 1024 * 1024);
    unsigned short* xb  = (unsigned short*)((char*)d_ws + (size_t)16 * 1024 * 1024 + 65536);
    const size_t need_xb = (size_t)16 * 1024 * 1024 + 65536 + (size_t)M_TOT * D_DIM * 2;
    const bool use_xb = (ws_size >= need_xb);

    prep_weights<<<4096, 256, 0, stream>>>(wkv, wgate, Wc);
    prep_ape<<<4, 256, 0, stream>>>(ape, ape_mean);

    if (use_xb) {
        prep_x<<<32768, 256, 0, stream>>>(x, xb);
        (void)hipFuncSetAttribute(
            reinterpret_cast<const void*>(&gemm_fused_8ph),
            hipFuncAttributeMaxDynamicSharedMemorySize, 131072);
        gemm_fused_8ph<<<(M_TOT / BM) * (N_TOT / BN), 512, 131072, stream>>>(
            xb, Wc, ape_mean, out);
    } else {
        gemm_fused_f32<<<dim3(N_TOT / 128, M_TOT / 128), 256, 0, stream>>>(
            x, Wc, ape_mean, out);
    }

    rmsnorm_inplace<<<2048, 256, 0, stream>>>(out, normw);
}

// Round 9
// 461.005 us; speedup vs baseline: 3.6754x; 3.6754x over previous
//
#include <hip/hip_runtime.h>
#include <hip/hip_bf16.h>

// Problem constants (B=4, S=4096, D=4096, r=4, COFF=2, HD=512)
#define D_DIM 4096
#define OD    1024          // COFF*HD combined projection width
#define M_TOT 16384         // B*S
#define N_TOT 2048          // 2*OD (kv/gate interleaved)
#define BM 256
#define BN 256
#define BK 64

#define GLOBAL_AS __attribute__((address_space(1)))
#define LDS_AS    __attribute__((address_space(3)))

typedef __attribute__((ext_vector_type(8))) short          bf16x8;
typedef __attribute__((ext_vector_type(8))) unsigned short u16x8;
typedef __attribute__((ext_vector_type(4))) float          f32x4;

__device__ __forceinline__ unsigned short f2bf(float f) {
    unsigned int u = __float_as_uint(f);
    u = (u + 0x7fffu + ((u >> 16) & 1u)) >> 16;
    return (unsigned short)u;
}

__device__ __forceinline__ float sigm(float x) {
    return 1.0f / (1.0f + __expf(-x));
}

__device__ __forceinline__ void gload16(const void* g, void* l) {
    __builtin_amdgcn_global_load_lds((const GLOBAL_AS void*)g, (LDS_AS void*)l, 16, 0, 0);
}

// ---- prep: interleave wkv/wgate rows into combined bf16 weight [2048][4096]
__global__ void prep_weights(const float* __restrict__ wkv,
                             const float* __restrict__ wgate,
                             unsigned short* __restrict__ Wc) {
    int t  = blockIdx.x * 256 + threadIdx.x;
    int n  = t >> 9;
    int k8 = t & 511;
    const float* src = (n & 1) ? wgate : wkv;
    const float4* s4 = (const float4*)(src + (size_t)(n >> 1) * D_DIM + k8 * 8);
    float4 a = s4[0], b = s4[1];
    u16x8 o;
    o[0] = f2bf(a.x); o[1] = f2bf(a.y); o[2] = f2bf(a.z); o[3] = f2bf(a.w);
    o[4] = f2bf(b.x); o[5] = f2bf(b.y); o[6] = f2bf(b.z); o[7] = f2bf(b.w);
    *(u16x8*)(Wc + (size_t)n * D_DIM + k8 * 8) = o;
}

// ---- prep: x fp32 -> bf16
__global__ void prep_x(const float* __restrict__ x, unsigned short* __restrict__ xb) {
    size_t t = (size_t)blockIdx.x * 256 + threadIdx.x;
    const float4* s = (const float4*)(x + t * 8);
    float4 a = s[0], b = s[1];
    u16x8 o;
    o[0] = f2bf(a.x); o[1] = f2bf(a.y); o[2] = f2bf(a.z); o[3] = f2bf(a.w);
    o[4] = f2bf(b.x); o[5] = f2bf(b.y); o[6] = f2bf(b.z); o[7] = f2bf(b.w);
    *(u16x8*)(xb + t * 8) = o;
}

// ---- prep: ape mean over the 4 window positions
__global__ void prep_ape(const float* __restrict__ ape, float* __restrict__ am) {
    int t = blockIdx.x * 256 + threadIdx.x;
    if (t < OD)
        am[t] = 0.25f * (ape[t] + ape[OD + t] + ape[2 * OD + t] + ape[3 * OD + t]);
}

// =====================================================================
// 256x256 / BK=64 / 8-wave / 4-phase GEMM (16x16x32 MFMA, r5 fragment
// geometry -> 0 bank conflicts). Phase = one qa half of the wave tile x
// FULL n-width: 16 ds_read_b128 (A-quad 8 + B-full 8) + 32 MFMA, all
// operands phase-local (64 transient VGPR, no cross-phase liveness ->
// no spill; r6/r8 lesson). 64 b128/iter vs r5's 96.
// Stage/vmcnt schedule (FIFO-traced; invariant: 2 outstanding at iter
// entry): ph1 stages buf1{A1,B0,B1}(6), ph2 stages buf0'A0(2)+vmcnt(2),
// ph3 stages buf0'{A1,B0}(4), ph4 stages buf0'B1+buf1'A0(4)+vmcnt(2).
// Every staged region's last read precedes its stage phase; wrapped
// final-iter stages touch only dead regions.
// =====================================================================
extern __shared__ __align__(16) unsigned short smem_u16[];

__global__ __launch_bounds__(512, 2)
void gemm_fused_4ph(const unsigned short* __restrict__ A,
                    const unsigned short* __restrict__ Wc,
                    const float* __restrict__ ape_mean,
                    float* __restrict__ out_pooled) {
    unsigned short* Asb[2] = {smem_u16,               smem_u16 + BM * BK};
    unsigned short* Bsb[2] = {smem_u16 + 2 * BM * BK, smem_u16 + 3 * BM * BK};

    const int tid  = threadIdx.x;
    const int lane = tid & 63;
    const int wave = tid >> 6;          // 8 waves: wm = wave>>2 (2), wn = wave&3 (4)
    const int wm   = wave >> 2;
    const int wn   = wave & 3;
    const int h    = lane & 15;
    const int q    = lane >> 4;

    // XCD partition by m: xcd = bid&7 owns m-tiles [xcd*8, xcd*8+8), all 8 n-tiles.
    const int bid = blockIdx.x;
    const int j   = bid >> 3;
    const int m0  = ((bid & 7) * 8 + (j >> 3)) * BM;
    const int n0  = (j & 7) * BN;

    // staging: pre-swizzled source chunk (rule 21 both-sides; verified r3)
    const int sc8 = (lane & 7) ^ ((lane >> 3) & 7);
    const unsigned short* Ag = A  + (size_t)(m0 + wave * 8 + (lane >> 3)) * D_DIM + sc8 * 8;
    const unsigned short* Bg = Wc + (size_t)(n0 + (wave & 3) * 8 + (lane >> 3)) * D_DIM + sc8 * 8;
    const int bstripe = wave >> 2;      // waves 0-3: stripes {0,2}; 4-7: {1,3}

#define STAGE_A(buf, half, kofs)                                                   \
    do {                                                                           \
        gload16(Ag + (size_t)((half) * 64) * D_DIM + (kofs),                       \
                Asb[buf] + ((half) * 64 + wave * 8) * BK);                         \
        gload16(Ag + (size_t)((half) * 64 + 128) * D_DIM + (kofs),                 \
                Asb[buf] + ((half) * 64 + 128 + wave * 8) * BK);                   \
    } while (0)

#define STAGE_B(buf, qb, kofs)                                                     \
    do {                                                                           \
        const int r0_ = (qb) * 32 + bstripe * 64;                                  \
        const int r1_ = (qb) * 32 + (2 + bstripe) * 64;                            \
        gload16(Bg + (size_t)r0_ * D_DIM + (kofs),                                 \
                Bsb[buf] + (r0_ + (wave & 3) * 8) * BK);                           \
        gload16(Bg + (size_t)r1_ * D_DIM + (kofs),                                 \
                Bsb[buf] + (r1_ + (wave & 3) * 8) * BK);                           \
    } while (0)

#define BAR() __builtin_amdgcn_s_barrier()
#define VMW2() asm volatile("s_waitcnt vmcnt(2)" ::: "memory")

// One phase: qa half of the wave tile, full n-width of buffer `buf`.
// 16 ds_read_b128 (all phase-local) + 32 MFMA. STAGECODE after reads;
// optional vmcnt before the mid-barrier.
#define PHASE(buf, qa, STAGECODE, VM)                                              \
    do {                                                                           \
        bf16x8 av[4][2], bv[4][2];                                                 \
        _Pragma("unroll")                                                          \
        for (int mi = 0; mi < 4; ++mi) {                                           \
            const int row = wm * 128 + ((qa) * 4 + mi) * 16 + h;                   \
            _Pragma("unroll")                                                      \
            for (int ks = 0; ks < 2; ++ks)                                         \
                av[mi][ks] = *(const bf16x8*)&Asb[buf][(row * BK + ks * 32 +       \
                             q * 8) ^ ((row & 7) << 3)];                           \
        }                                                                          \
        _Pragma("unroll")                                                          \
        for (int ni = 0; ni < 4; ++ni) {                                           \
            const int rw = wn * 64 + ni * 16 + h;                                  \
            _Pragma("unroll")                                                      \
            for (int ks = 0; ks < 2; ++ks)                                         \
                bv[ni][ks] = *(const bf16x8*)&Bsb[buf][(rw * BK + ks * 32 +        \
                             q * 8) ^ ((rw & 7) << 3)];                            \
        }                                                                          \
        STAGECODE;                                                                 \
        if (VM) VMW2();                                                            \
        BAR();                                                                     \
        __builtin_amdgcn_s_setprio(1);                                             \
        _Pragma("unroll")                                                          \
        for (int mi = 0; mi < 4; ++mi)                                             \
            _Pragma("unroll")                                                      \
            for (int ni = 0; ni < 4; ++ni)                                         \
                _Pragma("unroll")                                                  \
                for (int ks = 0; ks < 2; ++ks)                                     \
                    acc[(qa) * 4 + mi][ni] =                                       \
                        __builtin_amdgcn_mfma_f32_16x16x32_bf16(                   \
                            av[mi][ks], bv[ni][ks],                                \
                            acc[(qa) * 4 + mi][ni], 0, 0, 0);                      \
        __builtin_amdgcn_s_setprio(0);                                             \
        BAR();                                                                     \
    } while (0)

    f32x4 acc[8][4];
    const f32x4 z = {0.f, 0.f, 0.f, 0.f};
#pragma unroll
    for (int i = 0; i < 8; ++i)
#pragma unroll
        for (int jj = 0; jj < 4; ++jj) acc[i][jj] = z;

    // prologue: T0 full -> buf0 (8 loads), A0(T1) -> buf1 (2 loads).
    // vmcnt(2) leaves exactly A0(T1) outstanding = steady-state invariant.
    STAGE_A(0, 0, 0); STAGE_A(0, 1, 0); STAGE_B(0, 0, 0); STAGE_B(0, 1, 0);
    STAGE_A(1, 0, 64);
    VMW2();
    BAR();

    for (int kt2 = 0; kt2 < D_DIM; kt2 += 2 * BK) {
        const int kb1 = kt2 + BK;                // buf1 tile this iter (<= 4032)
        const int kna = (kt2 + 2 * BK) & 4095;   // next buf0 tile (wraps last trip)
        const int knb = (kt2 + 3 * BK) & 4095;   // next buf1 tile
        // ph1: read buf0 qa=0. Stage buf1 tile's A1,B0,B1 (read this iter ph3/4;
        //      regions' prev content last read in prev iter's ph4).
        PHASE(0, 0, { STAGE_A(1, 1, kb1); STAGE_B(1, 0, kb1); STAGE_B(1, 1, kb1); }, 0);
        // ph2: read buf0 qa=1. Stage next buf0 A0 (last read ph1). vmcnt(2):
        //      drains the 8 buf1 loads (prev-ph4's A0 + ph1's 6) before ph3.
        PHASE(0, 1, { STAGE_A(0, 0, kna); }, 1);
        // ph3: read buf1 qa=0. Stage next buf0 A1,B0 (buf0 fully read at ph2).
        PHASE(1, 0, { STAGE_A(0, 1, kna); STAGE_B(0, 0, kna); }, 0);
        // ph4: read buf1 qa=1. Stage next buf0 B1 + next buf1 A0 (buf1-A0 last
        //      read ph3). vmcnt(2): drains next-buf0's 8 loads before next ph1.
        PHASE(1, 1, { STAGE_B(0, 1, kna); STAGE_A(1, 0, knb); }, 1);
    }
#undef STAGE_A
#undef STAGE_B
#undef PHASE
#undef BAR
#undef VMW2

    // Epilogue: even combined-cols = kv, odd = gate (adjacent lanes).
    // Lane's 4 acc regs = rows q*4..q*4+3 = one r=4 pooling window.
    const bool is_kv = ((h & 1) == 0);
#pragma unroll
    for (int mi = 0; mi < 8; ++mi) {
        const int mbase = m0 + wm * 128 + mi * 16 + q * 4;
        const int wglob = mbase >> 2;
#pragma unroll
        for (int ni = 0; ni < 4; ++ni) {
            f32x4 kv = acc[mi][ni];
            float g0 = __shfl_xor(kv[0], 1);
            float g1 = __shfl_xor(kv[1], 1);
            float g2 = __shfl_xor(kv[2], 1);
            float g3 = __shfl_xor(kv[3], 1);
            if (is_kv) {
                float s = kv[0] * sigm(g0) + kv[1] * sigm(g1) +
                          kv[2] * sigm(g2) + kv[3] * sigm(g3);
                int n = n0 + wn * 64 + ni * 16 + h;   // even
                int o = n >> 1;
                out_pooled[(size_t)wglob * OD + o] = 0.25f * s + ape_mean[o];
            }
        }
    }
}

// ---- fallback (ws too small for xb): fp32 A + reg staging + XOR swizzle (r3)
__global__ __launch_bounds__(256)
void gemm_fused_f32(const float* __restrict__ Aptr,
                    const unsigned short* __restrict__ Wc,
                    const float* __restrict__ ape_mean,
                    float* __restrict__ out_pooled) {
    __shared__ __align__(16) unsigned short As[128 * BK];
    __shared__ __align__(16) unsigned short Bs[128 * BK];
    const int tid  = threadIdx.x;
    const int lane = tid & 63;
    const int wave = tid >> 6;
    const int wr   = wave >> 1;
    const int wc   = wave & 1;
    const int n0   = blockIdx.x * 128;
    const int m0   = blockIdx.y * 128;
    const int h    = lane & 15;
    const int q    = lane >> 4;

    f32x4 acc[4][4];
    const f32x4 z = {0.f, 0.f, 0.f, 0.f};
#pragma unroll
    for (int i = 0; i < 4; ++i)
#pragma unroll
        for (int jj = 0; jj < 4; ++jj) acc[i][jj] = z;

    for (int kt = 0; kt < D_DIM; kt += BK) {
#pragma unroll
        for (int i = 0; i < 4; ++i) {
            int chunk = tid + i * 256;
            int row = chunk >> 3, c8 = chunk & 7;
            int dst = (row * BK + c8 * 8) ^ ((row & 7) << 3);
            const float4* s = (const float4*)(Aptr + (size_t)(m0 + row) * D_DIM + kt + c8 * 8);
            float4 a = s[0], b = s[1];
            u16x8 o;
            o[0] = f2bf(a.x); o[1] = f2bf(a.y); o[2] = f2bf(a.z); o[3] = f2bf(a.w);
            o[4] = f2bf(b.x); o[5] = f2bf(b.y); o[6] = f2bf(b.z); o[7] = f2bf(b.w);
            *(u16x8*)&As[dst] = o;
        }
#pragma unroll
        for (int i = 0; i < 4; ++i) {
            int chunk = tid + i * 256;
            int row = chunk >> 3, c8 = chunk & 7;
            int dst = (row * BK + c8 * 8) ^ ((row & 7) << 3);
            *(u16x8*)&Bs[dst] =
                *(const u16x8*)(Wc + (size_t)(n0 + row) * D_DIM + kt + c8 * 8);
        }
        __syncthreads();
#pragma unroll
        for (int ks = 0; ks < 2; ++ks) {
            const int kb = ks * 32 + q * 8;
            bf16x8 af[4], bfr[4];
#pragma unroll
            for (int am = 0; am < 4; ++am) {
                int row = wr * 64 + am * 16 + h;
                af[am] = *(const bf16x8*)&As[(row * BK + kb) ^ ((row & 7) << 3)];
            }
#pragma unroll
            for (int bn = 0; bn < 4; ++bn) {
                int row = wc * 64 + bn * 16 + h;
                bfr[bn] = *(const bf16x8*)&Bs[(row * BK + kb) ^ ((row & 7) << 3)];
            }
#pragma unroll
            for (int am = 0; am < 4; ++am)
#pragma unroll
                for (int bn = 0; bn < 4; ++bn)
                    acc[am][bn] = __builtin_amdgcn_mfma_f32_16x16x32_bf16(
                        af[am], bfr[bn], acc[am][bn], 0, 0, 0);
        }
        __syncthreads();
    }
    const bool is_kv = ((h & 1) == 0);
#pragma unroll
    for (int am = 0; am < 4; ++am) {
        const int mbase = m0 + wr * 64 + am * 16 + q * 4;
        const int wglob = mbase >> 2;
#pragma unroll
        for (int bn = 0; bn < 4; ++bn) {
            f32x4 kv = acc[am][bn];
            float g0 = __shfl_xor(kv[0], 1);
            float g1 = __shfl_xor(kv[1], 1);
            float g2 = __shfl_xor(kv[2], 1);
            float g3 = __shfl_xor(kv[3], 1);
            if (is_kv) {
                float s = kv[0] * sigm(g0) + kv[1] * sigm(g1) +
                          kv[2] * sigm(g2) + kv[3] * sigm(g3);
                int n = n0 + wc * 64 + bn * 16 + h;
                int o = n >> 1;
                out_pooled[(size_t)wglob * OD + o] = 0.25f * s + ape_mean[o];
            }
        }
    }
}

// ---- in-place RMSNorm over head_dim=512 per token (8192 tokens)
__global__ void rmsnorm_inplace(float* __restrict__ out, const float* __restrict__ nw) {
    int token = blockIdx.x * 4 + (threadIdx.x >> 6);
    int lane  = threadIdx.x & 63;
    float4* p = (float4*)(out + (size_t)token * 512);
    float4 v0 = p[lane * 2], v1 = p[lane * 2 + 1];
    float ss = v0.x * v0.x + v0.y * v0.y + v0.z * v0.z + v0.w * v0.w +
               v1.x * v1.x + v1.y * v1.y + v1.z * v1.z + v1.w * v1.w;
#pragma unroll
    for (int off = 32; off > 0; off >>= 1) ss += __shfl_xor(ss, off);
    float rs = rsqrtf(ss * (1.0f / 512.0f) + 1e-6f);
    const float4* w4 = (const float4*)nw;
    float4 w0 = w4[lane * 2], w1 = w4[lane * 2 + 1];
    float4 r0, r1;
    r0.x = v0.x * rs * w0.x; r0.y = v0.y * rs * w0.y;
    r0.z = v0.z * rs * w0.z; r0.w = v0.w * rs * w0.w;
    r1.x = v1.x * rs * w1.x; r1.y = v1.y * rs * w1.y;
    r1.z = v1.z * rs * w1.z; r1.w = v1.w * rs * w1.w;
    p[lane * 2]     = r0;
    p[lane * 2 + 1] = r1;
}

extern "C" void kernel_launch(void* const* d_in, const int* in_sizes, int n_in,
                              void* d_out, int out_size, void* d_ws, size_t ws_size,
                              hipStream_t stream) {
    const float* x     = (const float*)d_in[0];
    const float* wkv   = (const float*)d_in[1];
    const float* wgate = (const float*)d_in[2];
    const float* ape   = (const float*)d_in[3];
    const float* normw = (const float*)d_in[4];
    float* out = (float*)d_out;

    unsigned short* Wc  = (unsigned short*)d_ws;
    float* ape_mean     = (float*)((char*)d_ws + (size_t)16 * 1024 * 1024);
    unsigned short* xb  = (unsigned short*)((char*)d_ws + (size_t)16 * 1024 * 1024 + 65536);
    const size_t need_xb = (size_t)16 * 1024 * 1024 + 65536 + (size_t)M_TOT * D_DIM * 2;
    const bool use_xb = (ws_size >= need_xb);

    prep_weights<<<4096, 256, 0, stream>>>(wkv, wgate, Wc);
    prep_ape<<<4, 256, 0, stream>>>(ape, ape_mean);

    if (use_xb) {
        prep_x<<<32768, 256, 0, stream>>>(x, xb);
        (void)hipFuncSetAttribute(
            reinterpret_cast<const void*>(&gemm_fused_4ph),
            hipFuncAttributeMaxDynamicSharedMemorySize, 131072);
        gemm_fused_4ph<<<(M_TOT / BM) * (N_TOT / BN), 512, 131072, stream>>>(
            xb, Wc, ape_mean, out);
    } else {
        gemm_fused_f32<<<dim3(N_TOT / 128, M_TOT / 128), 256, 0, stream>>>(
            x, Wc, ape_mean, out);
    }

    rmsnorm_inplace<<<2048, 256, 0, stream>>>(out, normw);
}

// Round 10
// 459.134 us; speedup vs baseline: 3.6903x; 1.0041x over previous
//
#include <hip/hip_runtime.h>
#include <hip/hip_bf16.h>

// Problem constants (B=4, S=4096, D=4096, r=4, COFF=2, HD=512)
#define D_DIM 4096
#define OD    1024          // COFF*HD combined projection width
#define M_TOT 16384         // B*S
#define N_TOT 2048          // 2*OD (kv/gate interleaved)
#define BM 256
#define BN 256
#define BK 64

#define GLOBAL_AS __attribute__((address_space(1)))
#define LDS_AS    __attribute__((address_space(3)))

typedef __attribute__((ext_vector_type(8))) short          bf16x8;
typedef __attribute__((ext_vector_type(8))) unsigned short u16x8;
typedef __attribute__((ext_vector_type(4))) float          f32x4;

__device__ __forceinline__ unsigned short f2bf(float f) {
    unsigned int u = __float_as_uint(f);
    u = (u + 0x7fffu + ((u >> 16) & 1u)) >> 16;
    return (unsigned short)u;
}

__device__ __forceinline__ float sigm(float x) {
    return 1.0f / (1.0f + __expf(-x));
}

__device__ __forceinline__ void gload16(const void* g, void* l) {
    __builtin_amdgcn_global_load_lds((const GLOBAL_AS void*)g, (LDS_AS void*)l, 16, 0, 0);
}

// ---- prep: interleave wkv/wgate rows into combined bf16 weight [2048][4096]
__global__ void prep_weights(const float* __restrict__ wkv,
                             const float* __restrict__ wgate,
                             unsigned short* __restrict__ Wc) {
    int t  = blockIdx.x * 256 + threadIdx.x;
    int n  = t >> 9;
    int k8 = t & 511;
    const float* src = (n & 1) ? wgate : wkv;
    const float4* s4 = (const float4*)(src + (size_t)(n >> 1) * D_DIM + k8 * 8);
    float4 a = s4[0], b = s4[1];
    u16x8 o;
    o[0] = f2bf(a.x); o[1] = f2bf(a.y); o[2] = f2bf(a.z); o[3] = f2bf(a.w);
    o[4] = f2bf(b.x); o[5] = f2bf(b.y); o[6] = f2bf(b.z); o[7] = f2bf(b.w);
    *(u16x8*)(Wc + (size_t)n * D_DIM + k8 * 8) = o;
}

// ---- prep: x fp32 -> bf16
__global__ void prep_x(const float* __restrict__ x, unsigned short* __restrict__ xb) {
    size_t t = (size_t)blockIdx.x * 256 + threadIdx.x;
    const float4* s = (const float4*)(x + t * 8);
    float4 a = s[0], b = s[1];
    u16x8 o;
    o[0] = f2bf(a.x); o[1] = f2bf(a.y); o[2] = f2bf(a.z); o[3] = f2bf(a.w);
    o[4] = f2bf(b.x); o[5] = f2bf(b.y); o[6] = f2bf(b.z); o[7] = f2bf(b.w);
    *(u16x8*)(xb + t * 8) = o;
}

// ---- prep: ape mean over the 4 window positions
__global__ void prep_ape(const float* __restrict__ ape, float* __restrict__ am) {
    int t = blockIdx.x * 256 + threadIdx.x;
    if (t < OD)
        am[t] = 0.25f * (ape[t] + ape[OD + t] + ape[2 * OD + t] + ape[3 * OD + t]);
}

// =====================================================================
// 256x256 / BK=64 / 8-wave / 4-phase GEMM (16x16x32 MFMA, r5 fragment
// geometry -> 0 bank conflicts). Phase = one qa half of the wave tile x
// FULL n-width: 16 ds_read_b128 (A-quad 8 + B-full 8) + 32 MFMA, all
// operands phase-local (64 transient VGPR, no cross-phase liveness ->
// no spill; r6/r8 lesson). 64 b128/iter vs r5's 96.
// Stage/vmcnt schedule (FIFO-traced; invariant: 2 outstanding at iter
// entry): ph1 stages buf1{A1,B0,B1}(6), ph2 stages buf0'A0(2)+vmcnt(2),
// ph3 stages buf0'{A1,B0}(4), ph4 stages buf0'B1+buf1'A0(4)+vmcnt(2).
// Every staged region's last read precedes its stage phase; wrapped
// final-iter stages touch only dead regions.
// =====================================================================
extern __shared__ __align__(16) unsigned short smem_u16[];

__global__ __launch_bounds__(512, 2)
void gemm_fused_4ph(const unsigned short* __restrict__ A,
                    const unsigned short* __restrict__ Wc,
                    const float* __restrict__ ape_mean,
                    float* __restrict__ out_pooled) {
    unsigned short* Asb[2] = {smem_u16,               smem_u16 + BM * BK};
    unsigned short* Bsb[2] = {smem_u16 + 2 * BM * BK, smem_u16 + 3 * BM * BK};

    const int tid  = threadIdx.x;
    const int lane = tid & 63;
    const int wave = tid >> 6;          // 8 waves: wm = wave>>2 (2), wn = wave&3 (4)
    const int wm   = wave >> 2;
    const int wn   = wave & 3;
    const int h    = lane & 15;
    const int q    = lane >> 4;

    // XCD partition by m: xcd = bid&7 owns m-tiles [xcd*8, xcd*8+8), all 8 n-tiles.
    const int bid = blockIdx.x;
    const int j   = bid >> 3;
    const int m0  = ((bid & 7) * 8 + (j >> 3)) * BM;
    const int n0  = (j & 7) * BN;

    // staging: pre-swizzled source chunk (rule 21 both-sides; verified r3)
    const int sc8 = (lane & 7) ^ ((lane >> 3) & 7);
    const unsigned short* Ag = A  + (size_t)(m0 + wave * 8 + (lane >> 3)) * D_DIM + sc8 * 8;
    const unsigned short* Bg = Wc + (size_t)(n0 + (wave & 3) * 8 + (lane >> 3)) * D_DIM + sc8 * 8;
    const int bstripe = wave >> 2;      // waves 0-3: stripes {0,2}; 4-7: {1,3}

#define STAGE_A(buf, half, kofs)                                                   \
    do {                                                                           \
        gload16(Ag + (size_t)((half) * 64) * D_DIM + (kofs),                       \
                Asb[buf] + ((half) * 64 + wave * 8) * BK);                         \
        gload16(Ag + (size_t)((half) * 64 + 128) * D_DIM + (kofs),                 \
                Asb[buf] + ((half) * 64 + 128 + wave * 8) * BK);                   \
    } while (0)

#define STAGE_B(buf, qb, kofs)                                                     \
    do {                                                                           \
        const int r0_ = (qb) * 32 + bstripe * 64;                                  \
        const int r1_ = (qb) * 32 + (2 + bstripe) * 64;                            \
        gload16(Bg + (size_t)r0_ * D_DIM + (kofs),                                 \
                Bsb[buf] + (r0_ + (wave & 3) * 8) * BK);                           \
        gload16(Bg + (size_t)r1_ * D_DIM + (kofs),                                 \
                Bsb[buf] + (r1_ + (wave & 3) * 8) * BK);                           \
    } while (0)

#define BAR() __builtin_amdgcn_s_barrier()
#define VMW2() asm volatile("s_waitcnt vmcnt(2)" ::: "memory")

// One phase: qa half of the wave tile, full n-width of buffer `buf`.
// 16 ds_read_b128 (all phase-local) + 32 MFMA. STAGECODE after reads;
// optional vmcnt before the mid-barrier.
#define PHASE(buf, qa, STAGECODE, VM)                                              \
    do {                                                                           \
        bf16x8 av[4][2], bv[4][2];                                                 \
        _Pragma("unroll")                                                          \
        for (int mi = 0; mi < 4; ++mi) {                                           \
            const int row = wm * 128 + ((qa) * 4 + mi) * 16 + h;                   \
            _Pragma("unroll")                                                      \
            for (int ks = 0; ks < 2; ++ks)                                         \
                av[mi][ks] = *(const bf16x8*)&Asb[buf][(row * BK + ks * 32 +       \
                             q * 8) ^ ((row & 7) << 3)];                           \
        }                                                                          \
        _Pragma("unroll")                                                          \
        for (int ni = 0; ni < 4; ++ni) {                                           \
            const int rw = wn * 64 + ni * 16 + h;                                  \
            _Pragma("unroll")                                                      \
            for (int ks = 0; ks < 2; ++ks)                                         \
                bv[ni][ks] = *(const bf16x8*)&Bsb[buf][(rw * BK + ks * 32 +        \
                             q * 8) ^ ((rw & 7) << 3)];                            \
        }                                                                          \
        STAGECODE;                                                                 \
        if (VM) VMW2();                                                            \
        BAR();                                                                     \
        __builtin_amdgcn_s_setprio(1);                                             \
        _Pragma("unroll")                                                          \
        for (int mi = 0; mi < 4; ++mi)                                             \
            _Pragma("unroll")                                                      \
            for (int ni = 0; ni < 4; ++ni)                                         \
                _Pragma("unroll")                                                  \
                for (int ks = 0; ks < 2; ++ks)                                     \
                    acc[(qa) * 4 + mi][ni] =                                       \
                        __builtin_amdgcn_mfma_f32_16x16x32_bf16(                   \
                            av[mi][ks], bv[ni][ks],                                \
                            acc[(qa) * 4 + mi][ni], 0, 0, 0);                      \
        __builtin_amdgcn_s_setprio(0);                                             \
        BAR();                                                                     \
    } while (0)

    f32x4 acc[8][4];
    const f32x4 z = {0.f, 0.f, 0.f, 0.f};
#pragma unroll
    for (int i = 0; i < 8; ++i)
#pragma unroll
        for (int jj = 0; jj < 4; ++jj) acc[i][jj] = z;

    // prologue: T0 full -> buf0 (8 loads), A0(T1) -> buf1 (2 loads).
    // vmcnt(2) leaves exactly A0(T1) outstanding = steady-state invariant.
    STAGE_A(0, 0, 0); STAGE_A(0, 1, 0); STAGE_B(0, 0, 0); STAGE_B(0, 1, 0);
    STAGE_A(1, 0, 64);
    VMW2();
    BAR();

    for (int kt2 = 0; kt2 < D_DIM; kt2 += 2 * BK) {
        const int kb1 = kt2 + BK;                // buf1 tile this iter (<= 4032)
        const int kna = (kt2 + 2 * BK) & 4095;   // next buf0 tile (wraps last trip)
        const int knb = (kt2 + 3 * BK) & 4095;   // next buf1 tile
        // ph1: read buf0 qa=0. Stage buf1 tile's A1,B0,B1 (read this iter ph3/4;
        //      regions' prev content last read in prev iter's ph4).
        PHASE(0, 0, { STAGE_A(1, 1, kb1); STAGE_B(1, 0, kb1); STAGE_B(1, 1, kb1); }, 0);
        // ph2: read buf0 qa=1. Stage next buf0 A0 (last read ph1). vmcnt(2):
        //      drains the 8 buf1 loads (prev-ph4's A0 + ph1's 6) before ph3.
        PHASE(0, 1, { STAGE_A(0, 0, kna); }, 1);
        // ph3: read buf1 qa=0. Stage next buf0 A1,B0 (buf0 fully read at ph2).
        PHASE(1, 0, { STAGE_A(0, 1, kna); STAGE_B(0, 0, kna); }, 0);
        // ph4: read buf1 qa=1. Stage next buf0 B1 + next buf1 A0 (buf1-A0 last
        //      read ph3). vmcnt(2): drains next-buf0's 8 loads before next ph1.
        PHASE(1, 1, { STAGE_B(0, 1, kna); STAGE_A(1, 0, knb); }, 1);
    }
#undef STAGE_A
#undef STAGE_B
#undef PHASE
#undef BAR
#undef VMW2

    // Epilogue: even combined-cols = kv, odd = gate (adjacent lanes).
    // Lane's 4 acc regs = rows q*4..q*4+3 = one r=4 pooling window.
    const bool is_kv = ((h & 1) == 0);
#pragma unroll
    for (int mi = 0; mi < 8; ++mi) {
        const int mbase = m0 + wm * 128 + mi * 16 + q * 4;
        const int wglob = mbase >> 2;
#pragma unroll
        for (int ni = 0; ni < 4; ++ni) {
            f32x4 kv = acc[mi][ni];
            float g0 = __shfl_xor(kv[0], 1);
            float g1 = __shfl_xor(kv[1], 1);
            float g2 = __shfl_xor(kv[2], 1);
            float g3 = __shfl_xor(kv[3], 1);
            if (is_kv) {
                float s = kv[0] * sigm(g0) + kv[1] * sigm(g1) +
                          kv[2] * sigm(g2) + kv[3] * sigm(g3);
                int n = n0 + wn * 64 + ni * 16 + h;   // even
                int o = n >> 1;
                out_pooled[(size_t)wglob * OD + o] = 0.25f * s + ape_mean[o];
            }
        }
    }
}

// ---- fallback (ws too small for xb): fp32 A + reg staging + XOR swizzle (r3)
__global__ __launch_bounds__(256)
void gemm_fused_f32(const float* __restrict__ Aptr,
                    const unsigned short* __restrict__ Wc,
                    const float* __restrict__ ape_mean,
                    float* __restrict__ out_pooled) {
    __shared__ __align__(16) unsigned short As[128 * BK];
    __shared__ __align__(16) unsigned short Bs[128 * BK];
    const int tid  = threadIdx.x;
    const int lane = tid & 63;
    const int wave = tid >> 6;
    const int wr   = wave >> 1;
    const int wc   = wave & 1;
    const int n0   = blockIdx.x * 128;
    const int m0   = blockIdx.y * 128;
    const int h    = lane & 15;
    const int q    = lane >> 4;

    f32x4 acc[4][4];
    const f32x4 z = {0.f, 0.f, 0.f, 0.f};
#pragma unroll
    for (int i = 0; i < 4; ++i)
#pragma unroll
        for (int jj = 0; jj < 4; ++jj) acc[i][jj] = z;

    for (int kt = 0; kt < D_DIM; kt += BK) {
#pragma unroll
        for (int i = 0; i < 4; ++i) {
            int chunk = tid + i * 256;
            int row = chunk >> 3, c8 = chunk & 7;
            int dst = (row * BK + c8 * 8) ^ ((row & 7) << 3);
            const float4* s = (const float4*)(Aptr + (size_t)(m0 + row) * D_DIM + kt + c8 * 8);
            float4 a = s[0], b = s[1];
            u16x8 o;
            o[0] = f2bf(a.x); o[1] = f2bf(a.y); o[2] = f2bf(a.z); o[3] = f2bf(a.w);
            o[4] = f2bf(b.x); o[5] = f2bf(b.y); o[6] = f2bf(b.z); o[7] = f2bf(b.w);
            *(u16x8*)&As[dst] = o;
        }
#pragma unroll
        for (int i = 0; i < 4; ++i) {
            int chunk = tid + i * 256;
            int row = chunk >> 3, c8 = chunk & 7;
            int dst = (row * BK + c8 * 8) ^ ((row & 7) << 3);
            *(u16x8*)&Bs[dst] =
                *(const u16x8*)(Wc + (size_t)(n0 + row) * D_DIM + kt + c8 * 8);
        }
        __syncthreads();
#pragma unroll
        for (int ks = 0; ks < 2; ++ks) {
            const int kb = ks * 32 + q * 8;
            bf16x8 af[4], bfr[4];
#pragma unroll
            for (int am = 0; am < 4; ++am) {
                int row = wr * 64 + am * 16 + h;
                af[am] = *(const bf16x8*)&As[(row * BK + kb) ^ ((row & 7) << 3)];
            }
#pragma unroll
            for (int bn = 0; bn < 4; ++bn) {
                int row = wc * 64 + bn * 16 + h;
                bfr[bn] = *(const bf16x8*)&Bs[(row * BK + kb) ^ ((row & 7) << 3)];
            }
#pragma unroll
            for (int am = 0; am < 4; ++am)
#pragma unroll
                for (int bn = 0; bn < 4; ++bn)
                    acc[am][bn] = __builtin_amdgcn_mfma_f32_16x16x32_bf16(
                        af[am], bfr[bn], acc[am][bn], 0, 0, 0);
        }
        __syncthreads();
    }
    const bool is_kv = ((h & 1) == 0);
#pragma unroll
    for (int am = 0; am < 4; ++am) {
        const int mbase = m0 + wr * 64 + am * 16 + q * 4;
        const int wglob = mbase >> 2;
#pragma unroll
        for (int bn = 0; bn < 4; ++bn) {
            f32x4 kv = acc[am][bn];
            float g0 = __shfl_xor(kv[0], 1);
            float g1 = __shfl_xor(kv[1], 1);
            float g2 = __shfl_xor(kv[2], 1);
            float g3 = __shfl_xor(kv[3], 1);
            if (is_kv) {
                float s = kv[0] * sigm(g0) + kv[1] * sigm(g1) +
                          kv[2] * sigm(g2) + kv[3] * sigm(g3);
                int n = n0 + wc * 64 + bn * 16 + h;
                int o = n >> 1;
                out_pooled[(size_t)wglob * OD + o] = 0.25f * s + ape_mean[o];
            }
        }
    }
}

// ---- in-place RMSNorm over head_dim=512 per token (8192 tokens)
__global__ void rmsnorm_inplace(float* __restrict__ out, const float* __restrict__ nw) {
    int token = blockIdx.x * 4 + (threadIdx.x >> 6);
    int lane  = threadIdx.x & 63;
    float4* p = (float4*)(out + (size_t)token * 512);
    float4 v0 = p[lane * 2], v1 = p[lane * 2 + 1];
    float ss = v0.x * v0.x + v0.y * v0.y + v0.z * v0.z + v0.w * v0.w +
               v1.x * v1.x + v1.y * v1.y + v1.z * v1.z + v1.w * v1.w;
#pragma unroll
    for (int off = 32; off > 0; off >>= 1) ss += __shfl_xor(ss, off);
    float rs = rsqrtf(ss * (1.0f / 512.0f) + 1e-6f);
    const float4* w4 = (const float4*)nw;
    float4 w0 = w4[lane * 2], w1 = w4[lane * 2 + 1];
    float4 r0, r1;
    r0.x = v0.x * rs * w0.x; r0.y = v0.y * rs * w0.y;
    r0.z = v0.z * rs * w0.z; r0.w = v0.w * rs * w0.w;
    r1.x = v1.x * rs * w1.x; r1.y = v1.y * rs * w1.y;
    r1.z = v1.z * rs * w1.z; r1.w = v1.w * rs * w1.w;
    p[lane * 2]     = r0;
    p[lane * 2 + 1] = r1;
}

extern "C" void kernel_launch(void* const* d_in, const int* in_sizes, int n_in,
                              void* d_out, int out_size, void* d_ws, size_t ws_size,
                              hipStream_t stream) {
    const float* x     = (const float*)d_in[0];
    const float* wkv   = (const float*)d_in[1];
    const float* wgate = (const float*)d_in[2];
    const float* ape   = (const float*)d_in[3];
    const float* normw = (const float*)d_in[4];
    float* out = (float*)d_out;

    unsigned short* Wc  = (unsigned short*)d_ws;
    float* ape_mean     = (float*)((char*)d_ws + (size_t)16 * 1024 * 1024);
    unsigned short* xb  = (unsigned short*)((char*)d_ws + (size_t)16 * 1024 * 1024 + 65536);
    const size_t need_xb = (size_t)16 * 1024 * 1024 + 65536 + (size_t)M_TOT * D_DIM * 2;
    const bool use_xb = (ws_size >= need_xb);

    prep_weights<<<4096, 256, 0, stream>>>(wkv, wgate, Wc);
    prep_ape<<<4, 256, 0, stream>>>(ape, ape_mean);

    if (use_xb) {
        prep_x<<<32768, 256, 0, stream>>>(x, xb);
        (void)hipFuncSetAttribute(
            reinterpret_cast<const void*>(&gemm_fused_4ph),
            hipFuncAttributeMaxDynamicSharedMemorySize, 131072);
        gemm_fused_4ph<<<(M_TOT / BM) * (N_TOT / BN), 512, 131072, stream>>>(
            xb, Wc, ape_mean, out);
    } else {
        gemm_fused_f32<<<dim3(N_TOT / 128, M_TOT / 128), 256, 0, stream>>>(
            x, Wc, ape_mean, out);
    }

    rmsnorm_inplace<<<2048, 256, 0, stream>>>(out, normw);
}

// Round 11
// 311.252 us; speedup vs baseline: 5.4437x; 1.4751x over previous
//
#include <hip/hip_runtime.h>
#include <hip/hip_bf16.h>

// Problem constants (B=4, S=4096, D=4096, r=4, COFF=2, HD=512)
#define D_DIM 4096
#define OD    1024          // COFF*HD combined projection width
#define M_TOT 16384         // B*S
#define N_TOT 2048          // 2*OD (kv/gate interleaved)
#define BM 256
#define BN 256
#define BK 64

#define GLOBAL_AS __attribute__((address_space(1)))
#define LDS_AS    __attribute__((address_space(3)))

typedef __attribute__((ext_vector_type(8))) short          bf16x8;
typedef __attribute__((ext_vector_type(8))) unsigned short u16x8;
typedef __attribute__((ext_vector_type(4))) float          f32x4;

__device__ __forceinline__ unsigned short f2bf(float f) {
    unsigned int u = __float_as_uint(f);
    u = (u + 0x7fffu + ((u >> 16) & 1u)) >> 16;
    return (unsigned short)u;
}

__device__ __forceinline__ float sigm(float x) {
    return 1.0f / (1.0f + __expf(-x));
}

__device__ __forceinline__ void gload16(const void* g, void* l) {
    __builtin_amdgcn_global_load_lds((const GLOBAL_AS void*)g, (LDS_AS void*)l, 16, 0, 0);
}

// ---- prep: interleave wkv/wgate rows into combined bf16 weight [2048][4096]
__global__ void prep_weights(const float* __restrict__ wkv,
                             const float* __restrict__ wgate,
                             unsigned short* __restrict__ Wc) {
    int t  = blockIdx.x * 256 + threadIdx.x;
    int n  = t >> 9;
    int k8 = t & 511;
    const float* src = (n & 1) ? wgate : wkv;
    const float4* s4 = (const float4*)(src + (size_t)(n >> 1) * D_DIM + k8 * 8);
    float4 a = s4[0], b = s4[1];
    u16x8 o;
    o[0] = f2bf(a.x); o[1] = f2bf(a.y); o[2] = f2bf(a.z); o[3] = f2bf(a.w);
    o[4] = f2bf(b.x); o[5] = f2bf(b.y); o[6] = f2bf(b.z); o[7] = f2bf(b.w);
    *(u16x8*)(Wc + (size_t)n * D_DIM + k8 * 8) = o;
}

// ---- prep: x fp32 -> bf16
__global__ void prep_x(const float* __restrict__ x, unsigned short* __restrict__ xb) {
    size_t t = (size_t)blockIdx.x * 256 + threadIdx.x;
    const float4* s = (const float4*)(x + t * 8);
    float4 a = s[0], b = s[1];
    u16x8 o;
    o[0] = f2bf(a.x); o[1] = f2bf(a.y); o[2] = f2bf(a.z); o[3] = f2bf(a.w);
    o[4] = f2bf(b.x); o[5] = f2bf(b.y); o[6] = f2bf(b.z); o[7] = f2bf(b.w);
    *(u16x8*)(xb + t * 8) = o;
}

// ---- prep: ape mean over the 4 window positions
__global__ void prep_ape(const float* __restrict__ ape, float* __restrict__ am) {
    int t = blockIdx.x * 256 + threadIdx.x;
    if (t < OD)
        am[t] = 0.25f * (ape[t] + ape[OD + t] + ape[2 * OD + t] + ape[3 * OD + t]);
}

// =====================================================================
// 256x256 / BK=64 / 8-wave / 8-phase GEMM (m201 operand-chain pattern).
// Per K-tile, quadrants (qa,qb) visited (0,0)->(1,0)->(1,1)->(0,1);
// each phase loads ONLY the changed operand group:
//   ph1: A0+B0 (12 ds_read_b128), ph2: A1 keep B0 (8), ph3: B1 keep A1
//   (4), ph4: A0 again keep B1 (8)  -> 32 b128/K-tile (r5: 48).
// Cross-barrier liveness <= 32 VGPR (one group); per-phase live peak 48
// (= r5's proven no-spill budget). 16 MFMA/phase, 16x16x32 fragments
// (0 bank conflicts, r5-verified).
// Stage schedule (every region's last read precedes its stage phase;
// FIFO invariant 6 outstanding at iter entry):
//   ph1->A0(Tb)buf1, ph2->B0'buf0, ph3->A1'buf0, ph4->B1'buf0+vmcnt(6)
//   (drains all 8 buf1 loads before ph5 reads buf1), ph5->A0'buf0,
//   ph6->B0''buf1, ph7->A1''buf1, ph8->B1''buf1+vmcnt(6).
// =====================================================================
extern __shared__ __align__(16) unsigned short smem_u16[];

__global__ __launch_bounds__(512, 2)
void gemm_fused_8ph(const unsigned short* __restrict__ A,
                    const unsigned short* __restrict__ Wc,
                    const float* __restrict__ ape_mean,
                    float* __restrict__ out_pooled) {
    unsigned short* Asb[2] = {smem_u16,               smem_u16 + BM * BK};
    unsigned short* Bsb[2] = {smem_u16 + 2 * BM * BK, smem_u16 + 3 * BM * BK};

    const int tid  = threadIdx.x;
    const int lane = tid & 63;
    const int wave = tid >> 6;          // 8 waves: wm = wave>>2 (2), wn = wave&3 (4)
    const int wm   = wave >> 2;
    const int wn   = wave & 3;
    const int h    = lane & 15;
    const int q    = lane >> 4;

    // XCD partition by m: xcd = bid&7 owns m-tiles [xcd*8, xcd*8+8), all 8 n-tiles.
    const int bid = blockIdx.x;
    const int j   = bid >> 3;
    const int m0  = ((bid & 7) * 8 + (j >> 3)) * BM;
    const int n0  = (j & 7) * BN;

    // staging: pre-swizzled source chunk (rule 21 both-sides; verified r3)
    const int sc8 = (lane & 7) ^ ((lane >> 3) & 7);
    const unsigned short* Ag = A  + (size_t)(m0 + wave * 8 + (lane >> 3)) * D_DIM + sc8 * 8;
    const unsigned short* Bg = Wc + (size_t)(n0 + (wave & 3) * 8 + (lane >> 3)) * D_DIM + sc8 * 8;
    const int bstripe = wave >> 2;      // waves 0-3: stripes {0,2}; 4-7: {1,3}

#define STAGE_A(buf, half, kofs)                                                   \
    do {                                                                           \
        gload16(Ag + (size_t)((half) * 64) * D_DIM + (kofs),                       \
                Asb[buf] + ((half) * 64 + wave * 8) * BK);                         \
        gload16(Ag + (size_t)((half) * 64 + 128) * D_DIM + (kofs),                 \
                Asb[buf] + ((half) * 64 + 128 + wave * 8) * BK);                   \
    } while (0)

#define STAGE_B(buf, qb, kofs)                                                     \
    do {                                                                           \
        const int r0_ = (qb) * 32 + bstripe * 64;                                  \
        const int r1_ = (qb) * 32 + (2 + bstripe) * 64;                            \
        gload16(Bg + (size_t)r0_ * D_DIM + (kofs),                                 \
                Bsb[buf] + (r0_ + (wave & 3) * 8) * BK);                           \
        gload16(Bg + (size_t)r1_ * D_DIM + (kofs),                                 \
                Bsb[buf] + (r1_ + (wave & 3) * 8) * BK);                           \
    } while (0)

#define LOAD_A(buf, qa, dst)                                                       \
    do {                                                                           \
        _Pragma("unroll")                                                          \
        for (int mi = 0; mi < 4; ++mi) {                                           \
            const int row = wm * 128 + ((qa) * 4 + mi) * 16 + h;                   \
            _Pragma("unroll")                                                      \
            for (int ks = 0; ks < 2; ++ks)                                         \
                dst[mi][ks] = *(const bf16x8*)&Asb[buf][(row * BK + ks * 32 +      \
                              q * 8) ^ ((row & 7) << 3)];                          \
        }                                                                          \
    } while (0)

#define LOAD_B(buf, qb, dst)                                                       \
    do {                                                                           \
        _Pragma("unroll")                                                          \
        for (int ni = 0; ni < 2; ++ni) {                                           \
            const int rw = wn * 64 + ((qb) * 2 + ni) * 16 + h;                     \
            _Pragma("unroll")                                                      \
            for (int ks = 0; ks < 2; ++ks)                                         \
                dst[ni][ks] = *(const bf16x8*)&Bsb[buf][(rw * BK + ks * 32 +       \
                              q * 8) ^ ((rw & 7) << 3)];                           \
        }                                                                          \
    } while (0)

#define MFMA_Q(qa, qb, asrc, bsrc)                                                 \
    do {                                                                           \
        __builtin_amdgcn_s_setprio(1);                                             \
        _Pragma("unroll")                                                          \
        for (int mi = 0; mi < 4; ++mi)                                             \
            _Pragma("unroll")                                                      \
            for (int ni = 0; ni < 2; ++ni)                                         \
                _Pragma("unroll")                                                  \
                for (int ks = 0; ks < 2; ++ks)                                     \
                    acc[(qa) * 4 + mi][(qb) * 2 + ni] =                            \
                        __builtin_amdgcn_mfma_f32_16x16x32_bf16(                   \
                            asrc[mi][ks], bsrc[ni][ks],                            \
                            acc[(qa) * 4 + mi][(qb) * 2 + ni], 0, 0, 0);           \
        __builtin_amdgcn_s_setprio(0);                                             \
    } while (0)

#define BAR() __builtin_amdgcn_s_barrier()
#define VMW6() asm volatile("s_waitcnt vmcnt(6)" ::: "memory")

    f32x4 acc[8][4];
    const f32x4 z = {0.f, 0.f, 0.f, 0.f};
#pragma unroll
    for (int i = 0; i < 8; ++i)
#pragma unroll
        for (int jj = 0; jj < 4; ++jj) acc[i][jj] = z;

    // prologue: buf0 <- T0 full (8 loads), buf1 <- T1 {B0,A1,B1} (6 loads).
    // vmcnt(6): buf0's 8 complete, buf1's 6 outstanding = steady invariant.
    STAGE_A(0, 0, 0); STAGE_A(0, 1, 0); STAGE_B(0, 0, 0); STAGE_B(0, 1, 0);
    STAGE_B(1, 0, 64); STAGE_A(1, 1, 64); STAGE_B(1, 1, 64);
    VMW6();
    BAR();

    for (int kt2 = 0; kt2 < D_DIM; kt2 += 2 * BK) {
        const int kb1 = kt2 + BK;                // buf1 tile this iter (<= 4032)
        const int kna = (kt2 + 2 * BK) & 4095;   // next buf0 tile (wraps: dead)
        const int knb = (kt2 + 3 * BK) & 4095;   // next buf1 tile (wraps: dead)
        bf16x8 av[4][2], bv[2][2];

        // ---- K-tile a (buf0): (0,0) -> (1,0) -> (1,1) -> (0,1) ----
        LOAD_A(0, 0, av); LOAD_B(0, 0, bv);      // 12 reads
        STAGE_A(1, 0, kb1);                      // ph1: A0(Tb)->buf1 (read ph5/8)
        BAR(); MFMA_Q(0, 0, av, bv); BAR();
        LOAD_A(0, 1, av);                        // 8 reads, keep bv=B0
        STAGE_B(0, 0, kna);                      // ph2: B0'->buf0 (B0 read ph1)
        BAR(); MFMA_Q(1, 0, av, bv); BAR();
        LOAD_B(0, 1, bv);                        // 4 reads, keep av=A1
        STAGE_A(0, 1, kna);                      // ph3: A1'->buf0 (A1 read ph2)
        BAR(); MFMA_Q(1, 1, av, bv); BAR();
        LOAD_A(0, 0, av);                        // 8 reads (A0 again), keep bv=B1
        STAGE_B(0, 1, kna);                      // ph4: B1'->buf0 (B1 read ph3)
        VMW6();                                  // all 8 buf1(Tb) loads complete
        BAR(); MFMA_Q(0, 1, av, bv); BAR();

        // ---- K-tile b (buf1): same chain ----
        LOAD_A(1, 0, av); LOAD_B(1, 0, bv);
        STAGE_A(0, 0, kna);                      // ph5: A0'->buf0 (A0 read ph1,4)
        BAR(); MFMA_Q(0, 0, av, bv); BAR();
        LOAD_A(1, 1, av);
        STAGE_B(1, 0, knb);                      // ph6: B0''->buf1 (B0 read ph5)
        BAR(); MFMA_Q(1, 0, av, bv); BAR();
        LOAD_B(1, 1, bv);
        STAGE_A(1, 1, knb);                      // ph7: A1''->buf1 (A1 read ph6)
        BAR(); MFMA_Q(1, 1, av, bv); BAR();
        LOAD_A(1, 0, av);
        STAGE_B(1, 1, knb);                      // ph8: B1''->buf1 (B1 read ph7)
        VMW6();                                  // all 8 buf0(Tna) loads complete
        BAR(); MFMA_Q(0, 1, av, bv); BAR();
    }
#undef STAGE_A
#undef STAGE_B
#undef LOAD_A
#undef LOAD_B
#undef MFMA_Q
#undef BAR
#undef VMW6

    // Epilogue: even combined-cols = kv, odd = gate (adjacent lanes).
    // Lane's 4 acc regs = rows q*4..q*4+3 = one r=4 pooling window.
    const bool is_kv = ((h & 1) == 0);
#pragma unroll
    for (int mi = 0; mi < 8; ++mi) {
        const int mbase = m0 + wm * 128 + mi * 16 + q * 4;
        const int wglob = mbase >> 2;
#pragma unroll
        for (int ni = 0; ni < 4; ++ni) {
            f32x4 kv = acc[mi][ni];
            float g0 = __shfl_xor(kv[0], 1);
            float g1 = __shfl_xor(kv[1], 1);
            float g2 = __shfl_xor(kv[2], 1);
            float g3 = __shfl_xor(kv[3], 1);
            if (is_kv) {
                float s = kv[0] * sigm(g0) + kv[1] * sigm(g1) +
                          kv[2] * sigm(g2) + kv[3] * sigm(g3);
                int n = n0 + wn * 64 + ni * 16 + h;   // even
                int o = n >> 1;
                out_pooled[(size_t)wglob * OD + o] = 0.25f * s + ape_mean[o];
            }
        }
    }
}

// ---- fallback (ws too small for xb): fp32 A + reg staging + XOR swizzle (r3)
__global__ __launch_bounds__(256)
void gemm_fused_f32(const float* __restrict__ Aptr,
                    const unsigned short* __restrict__ Wc,
                    const float* __restrict__ ape_mean,
                    float* __restrict__ out_pooled) {
    __shared__ __align__(16) unsigned short As[128 * BK];
    __shared__ __align__(16) unsigned short Bs[128 * BK];
    const int tid  = threadIdx.x;
    const int lane = tid & 63;
    const int wave = tid >> 6;
    const int wr   = wave >> 1;
    const int wc   = wave & 1;
    const int n0   = blockIdx.x * 128;
    const int m0   = blockIdx.y * 128;
    const int h    = lane & 15;
    const int q    = lane >> 4;

    f32x4 acc[4][4];
    const f32x4 z = {0.f, 0.f, 0.f, 0.f};
#pragma unroll
    for (int i = 0; i < 4; ++i)
#pragma unroll
        for (int jj = 0; jj < 4; ++jj) acc[i][jj] = z;

    for (int kt = 0; kt < D_DIM; kt += BK) {
#pragma unroll
        for (int i = 0; i < 4; ++i) {
            int chunk = tid + i * 256;
            int row = chunk >> 3, c8 = chunk & 7;
            int dst = (row * BK + c8 * 8) ^ ((row & 7) << 3);
            const float4* s = (const float4*)(Aptr + (size_t)(m0 + row) * D_DIM + kt + c8 * 8);
            float4 a = s[0], b = s[1];
            u16x8 o;
            o[0] = f2bf(a.x); o[1] = f2bf(a.y); o[2] = f2bf(a.z); o[3] = f2bf(a.w);
            o[4] = f2bf(b.x); o[5] = f2bf(b.y); o[6] = f2bf(b.z); o[7] = f2bf(b.w);
            *(u16x8*)&As[dst] = o;
        }
#pragma unroll
        for (int i = 0; i < 4; ++i) {
            int chunk = tid + i * 256;
            int row = chunk >> 3, c8 = chunk & 7;
            int dst = (row * BK + c8 * 8) ^ ((row & 7) << 3);
            *(u16x8*)&Bs[dst] =
                *(const u16x8*)(Wc + (size_t)(n0 + row) * D_DIM + kt + c8 * 8);
        }
        __syncthreads();
#pragma unroll
        for (int ks = 0; ks < 2; ++ks) {
            const int kb = ks * 32 + q * 8;
            bf16x8 af[4], bfr[4];
#pragma unroll
            for (int am = 0; am < 4; ++am) {
                int row = wr * 64 + am * 16 + h;
                af[am] = *(const bf16x8*)&As[(row * BK + kb) ^ ((row & 7) << 3)];
            }
#pragma unroll
            for (int bn = 0; bn < 4; ++bn) {
                int row = wc * 64 + bn * 16 + h;
                bfr[bn] = *(const bf16x8*)&Bs[(row * BK + kb) ^ ((row & 7) << 3)];
            }
#pragma unroll
            for (int am = 0; am < 4; ++am)
#pragma unroll
                for (int bn = 0; bn < 4; ++bn)
                    acc[am][bn] = __builtin_amdgcn_mfma_f32_16x16x32_bf16(
                        af[am], bfr[bn], acc[am][bn], 0, 0, 0);
        }
        __syncthreads();
    }
    const bool is_kv = ((h & 1) == 0);
#pragma unroll
    for (int am = 0; am < 4; ++am) {
        const int mbase = m0 + wr * 64 + am * 16 + q * 4;
        const int wglob = mbase >> 2;
#pragma unroll
        for (int bn = 0; bn < 4; ++bn) {
            f32x4 kv = acc[am][bn];
            float g0 = __shfl_xor(kv[0], 1);
            float g1 = __shfl_xor(kv[1], 1);
            float g2 = __shfl_xor(kv[2], 1);
            float g3 = __shfl_xor(kv[3], 1);
            if (is_kv) {
                float s = kv[0] * sigm(g0) + kv[1] * sigm(g1) +
                          kv[2] * sigm(g2) + kv[3] * sigm(g3);
                int n = n0 + wc * 64 + bn * 16 + h;
                int o = n >> 1;
                out_pooled[(size_t)wglob * OD + o] = 0.25f * s + ape_mean[o];
            }
        }
    }
}

// ---- in-place RMSNorm over head_dim=512 per token (8192 tokens)
__global__ void rmsnorm_inplace(float* __restrict__ out, const float* __restrict__ nw) {
    int token = blockIdx.x * 4 + (threadIdx.x >> 6);
    int lane  = threadIdx.x & 63;
    float4* p = (float4*)(out + (size_t)token * 512);
    float4 v0 = p[lane * 2], v1 = p[lane * 2 + 1];
    float ss = v0.x * v0.x + v0.y * v0.y + v0.z * v0.z + v0.w * v0.w +
               v1.x * v1.x + v1.y * v1.y + v1.z * v1.z + v1.w * v1.w;
#pragma unroll
    for (int off = 32; off > 0; off >>= 1) ss += __shfl_xor(ss, off);
    float rs = rsqrtf(ss * (1.0f / 512.0f) + 1e-6f);
    const float4* w4 = (const float4*)nw;
    float4 w0 = w4[lane * 2], w1 = w4[lane * 2 + 1];
    float4 r0, r1;
    r0.x = v0.x * rs * w0.x; r0.y = v0.y * rs * w0.y;
    r0.z = v0.z * rs * w0.z; r0.w = v0.w * rs * w0.w;
    r1.x = v1.x * rs * w1.x; r1.y = v1.y * rs * w1.y;
    r1.z = v1.z * rs * w1.z; r1.w = v1.w * rs * w1.w;
    p[lane * 2]     = r0;
    p[lane * 2 + 1] = r1;
}

extern "C" void kernel_launch(void* const* d_in, const int* in_sizes, int n_in,
                              void* d_out, int out_size, void* d_ws, size_t ws_size,
                              hipStream_t stream) {
    const float* x     = (const float*)d_in[0];
    const float* wkv   = (const float*)d_in[1];
    const float* wgate = (const float*)d_in[2];
    const float* ape   = (const float*)d_in[3];
    const float* normw = (const float*)d_in[4];
    float* out = (float*)d_out;

    unsigned short* Wc  = (unsigned short*)d_ws;
    float* ape_mean     = (float*)((char*)d_ws + (size_t)16 * 1024 * 1024);
    unsigned short* xb  = (unsigned short*)((char*)d_ws + (size_t)16 * 1024 * 1024 + 65536);
    const size_t need_xb = (size_t)16 * 1024 * 1024 + 65536 + (size_t)M_TOT * D_DIM * 2;
    const bool use_xb = (ws_size >= need_xb);

    prep_weights<<<4096, 256, 0, stream>>>(wkv, wgate, Wc);
    prep_ape<<<4, 256, 0, stream>>>(ape, ape_mean);

    if (use_xb) {
        prep_x<<<32768, 256, 0, stream>>>(x, xb);
        (void)hipFuncSetAttribute(
            reinterpret_cast<const void*>(&gemm_fused_8ph),
            hipFuncAttributeMaxDynamicSharedMemorySize, 131072);
        gemm_fused_8ph<<<(M_TOT / BM) * (N_TOT / BN), 512, 131072, stream>>>(
            xb, Wc, ape_mean, out);
    } else {
        gemm_fused_f32<<<dim3(N_TOT / 128, M_TOT / 128), 256, 0, stream>>>(
            x, Wc, ape_mean, out);
    }

    rmsnorm_inplace<<<2048, 256, 0, stream>>>(out, normw);
}

// Round 12
// 308.332 us; speedup vs baseline: 5.4953x; 1.0095x over previous
//
#include <hip/hip_runtime.h>
#include <hip/hip_bf16.h>

// Problem constants (B=4, S=4096, D=4096, r=4, COFF=2, HD=512)
#define D_DIM 4096
#define OD    1024          // COFF*HD combined projection width
#define M_TOT 16384         // B*S
#define N_TOT 2048          // 2*OD (kv/gate interleaved)
#define BM 256
#define BN 256
#define BK 64

#define GLOBAL_AS __attribute__((address_space(1)))
#define LDS_AS    __attribute__((address_space(3)))

typedef __attribute__((ext_vector_type(8))) short          bf16x8;
typedef __attribute__((ext_vector_type(8))) unsigned short u16x8;
typedef __attribute__((ext_vector_type(4))) float          f32x4;

__device__ __forceinline__ unsigned short f2bf(float f) {
    unsigned int u = __float_as_uint(f);
    u = (u + 0x7fffu + ((u >> 16) & 1u)) >> 16;
    return (unsigned short)u;
}

__device__ __forceinline__ float sigm(float x) {
    return 1.0f / (1.0f + __expf(-x));
}

__device__ __forceinline__ void gload16(const void* g, void* l) {
    __builtin_amdgcn_global_load_lds((const GLOBAL_AS void*)g, (LDS_AS void*)l, 16, 0, 0);
}

// ---- prep: interleave wkv/wgate rows into combined bf16 weight [2048][4096]
__global__ void prep_weights(const float* __restrict__ wkv,
                             const float* __restrict__ wgate,
                             unsigned short* __restrict__ Wc) {
    int t  = blockIdx.x * 256 + threadIdx.x;
    int n  = t >> 9;
    int k8 = t & 511;
    const float* src = (n & 1) ? wgate : wkv;
    const float4* s4 = (const float4*)(src + (size_t)(n >> 1) * D_DIM + k8 * 8);
    float4 a = s4[0], b = s4[1];
    u16x8 o;
    o[0] = f2bf(a.x); o[1] = f2bf(a.y); o[2] = f2bf(a.z); o[3] = f2bf(a.w);
    o[4] = f2bf(b.x); o[5] = f2bf(b.y); o[6] = f2bf(b.z); o[7] = f2bf(b.w);
    *(u16x8*)(Wc + (size_t)n * D_DIM + k8 * 8) = o;
}

// ---- prep: x fp32 -> bf16
__global__ void prep_x(const float* __restrict__ x, unsigned short* __restrict__ xb) {
    size_t t = (size_t)blockIdx.x * 256 + threadIdx.x;
    const float4* s = (const float4*)(x + t * 8);
    float4 a = s[0], b = s[1];
    u16x8 o;
    o[0] = f2bf(a.x); o[1] = f2bf(a.y); o[2] = f2bf(a.z); o[3] = f2bf(a.w);
    o[4] = f2bf(b.x); o[5] = f2bf(b.y); o[6] = f2bf(b.z); o[7] = f2bf(b.w);
    *(u16x8*)(xb + t * 8) = o;
}

// ---- prep: ape mean over the 4 window positions
__global__ void prep_ape(const float* __restrict__ ape, float* __restrict__ am) {
    int t = blockIdx.x * 256 + threadIdx.x;
    if (t < OD)
        am[t] = 0.25f * (ape[t] + ape[OD + t] + ape[2 * OD + t] + ape[3 * OD + t]);
}

// =====================================================================
// 256x256 / BK=64 / 8-wave / 8-phase GEMM, operand-chain order with
// B0 (4-read group) as the re-read quadrant: per K-tile, (qa,qb) visit
// (0,0)->(0,1)->(1,1)->(1,0):
//   ph1: A0+B0 (12 ds_read_b128), ph2: B1 keep A0 (4), ph3: A1 keep B1
//   (8), ph4: B0 again keep A1 (4) -> 28 b128/K-tile (r11: 32).
// Carried groups A0(32)->B1(16)->A1(32); per-phase live peak 48 VGPR
// (r5/r11-proven no-spill budget). 16 MFMA/phase, 16x16x32 fragments.
// LDS-region deaths: buf0 A0+ph1, B1+ph2, A1+ph3, B0+ph4 (buf1 mirrors
// ph5-8). Uniform stage map, 2 gloads/phase (m201 shape):
//   ph1->B0(Tb)buf1, ph2->A0'buf0, ph3->B1'buf0, ph4->A1'buf0+vmcnt(6)
//   (14 outstanding, waits exactly the 8 buf1(Tb) loads),
//   ph5->B0'buf0, ph6->A0(Tnb)buf1, ph7->B1(Tnb)buf1,
//   ph8->A1(Tnb)buf1+vmcnt(6) (waits the 8 buf0(Tna) loads).
// Every stage >= 1 phase after its region's last LDS read.
// =====================================================================
extern __shared__ __align__(16) unsigned short smem_u16[];

__global__ __launch_bounds__(512, 2)
void gemm_fused_8ph(const unsigned short* __restrict__ A,
                    const unsigned short* __restrict__ Wc,
                    const float* __restrict__ ape_mean,
                    float* __restrict__ out_pooled) {
    unsigned short* Asb[2] = {smem_u16,               smem_u16 + BM * BK};
    unsigned short* Bsb[2] = {smem_u16 + 2 * BM * BK, smem_u16 + 3 * BM * BK};

    const int tid  = threadIdx.x;
    const int lane = tid & 63;
    const int wave = tid >> 6;          // 8 waves: wm = wave>>2 (2), wn = wave&3 (4)
    const int wm   = wave >> 2;
    const int wn   = wave & 3;
    const int h    = lane & 15;
    const int q    = lane >> 4;

    // XCD partition by m: xcd = bid&7 owns m-tiles [xcd*8, xcd*8+8), all 8 n-tiles.
    const int bid = blockIdx.x;
    const int j   = bid >> 3;
    const int m0  = ((bid & 7) * 8 + (j >> 3)) * BM;
    const int n0  = (j & 7) * BN;

    // staging: pre-swizzled source chunk (rule 21 both-sides; verified r3)
    const int sc8 = (lane & 7) ^ ((lane >> 3) & 7);
    const unsigned short* Ag = A  + (size_t)(m0 + wave * 8 + (lane >> 3)) * D_DIM + sc8 * 8;
    const unsigned short* Bg = Wc + (size_t)(n0 + (wave & 3) * 8 + (lane >> 3)) * D_DIM + sc8 * 8;
    const int bstripe = wave >> 2;      // waves 0-3: stripes {0,2}; 4-7: {1,3}

#define STAGE_A(buf, half, kofs)                                                   \
    do {                                                                           \
        gload16(Ag + (size_t)((half) * 64) * D_DIM + (kofs),                       \
                Asb[buf] + ((half) * 64 + wave * 8) * BK);                         \
        gload16(Ag + (size_t)((half) * 64 + 128) * D_DIM + (kofs),                 \
                Asb[buf] + ((half) * 64 + 128 + wave * 8) * BK);                   \
    } while (0)

#define STAGE_B(buf, qb, kofs)                                                     \
    do {                                                                           \
        const int r0_ = (qb) * 32 + bstripe * 64;                                  \
        const int r1_ = (qb) * 32 + (2 + bstripe) * 64;                            \
        gload16(Bg + (size_t)r0_ * D_DIM + (kofs),                                 \
                Bsb[buf] + (r0_ + (wave & 3) * 8) * BK);                           \
        gload16(Bg + (size_t)r1_ * D_DIM + (kofs),                                 \
                Bsb[buf] + (r1_ + (wave & 3) * 8) * BK);                           \
    } while (0)

#define LOAD_A(buf, qa, dst)                                                       \
    do {                                                                           \
        _Pragma("unroll")                                                          \
        for (int mi = 0; mi < 4; ++mi) {                                           \
            const int row = wm * 128 + ((qa) * 4 + mi) * 16 + h;                   \
            _Pragma("unroll")                                                      \
            for (int ks = 0; ks < 2; ++ks)                                         \
                dst[mi][ks] = *(const bf16x8*)&Asb[buf][(row * BK + ks * 32 +      \
                              q * 8) ^ ((row & 7) << 3)];                          \
        }                                                                          \
    } while (0)

#define LOAD_B(buf, qb, dst)                                                       \
    do {                                                                           \
        _Pragma("unroll")                                                          \
        for (int ni = 0; ni < 2; ++ni) {                                           \
            const int rw = wn * 64 + ((qb) * 2 + ni) * 16 + h;                     \
            _Pragma("unroll")                                                      \
            for (int ks = 0; ks < 2; ++ks)                                         \
                dst[ni][ks] = *(const bf16x8*)&Bsb[buf][(rw * BK + ks * 32 +       \
                              q * 8) ^ ((rw & 7) << 3)];                           \
        }                                                                          \
    } while (0)

#define MFMA_Q(qa, qb, asrc, bsrc)                                                 \
    do {                                                                           \
        __builtin_amdgcn_s_setprio(1);                                             \
        _Pragma("unroll")                                                          \
        for (int mi = 0; mi < 4; ++mi)                                             \
            _Pragma("unroll")                                                      \
            for (int ni = 0; ni < 2; ++ni)                                         \
                _Pragma("unroll")                                                  \
                for (int ks = 0; ks < 2; ++ks)                                     \
                    acc[(qa) * 4 + mi][(qb) * 2 + ni] =                            \
                        __builtin_amdgcn_mfma_f32_16x16x32_bf16(                   \
                            asrc[mi][ks], bsrc[ni][ks],                            \
                            acc[(qa) * 4 + mi][(qb) * 2 + ni], 0, 0, 0);           \
        __builtin_amdgcn_s_setprio(0);                                             \
    } while (0)

#define BAR() __builtin_amdgcn_s_barrier()
#define VMW6() asm volatile("s_waitcnt vmcnt(6)" ::: "memory")

    f32x4 acc[8][4];
    const f32x4 z = {0.f, 0.f, 0.f, 0.f};
#pragma unroll
    for (int i = 0; i < 8; ++i)
#pragma unroll
        for (int jj = 0; jj < 4; ++jj) acc[i][jj] = z;

    // prologue: buf0 <- T0 full (8 loads), buf1 <- T1 {A0,B1,A1} (6 loads)
    // (steady-state equivalents of ph6/ph7/ph8 stages). vmcnt(6): buf0's 8
    // complete, buf1's 6 outstanding = steady iter-entry invariant.
    STAGE_A(0, 0, 0); STAGE_A(0, 1, 0); STAGE_B(0, 0, 0); STAGE_B(0, 1, 0);
    STAGE_A(1, 0, 64); STAGE_B(1, 1, 64); STAGE_A(1, 1, 64);
    VMW6();
    BAR();

    for (int kt2 = 0; kt2 < D_DIM; kt2 += 2 * BK) {
        const int kb1 = kt2 + BK;                // buf1 tile this iter (<= 4032)
        const int kna = (kt2 + 2 * BK) & 4095;   // next buf0 tile (wraps: dead)
        const int knb = (kt2 + 3 * BK) & 4095;   // next buf1 tile (wraps: dead)
        bf16x8 av[4][2], bv[2][2];

        // ---- K-tile a (buf0): (0,0) -> (0,1) -> (1,1) -> (1,0) ----
        LOAD_A(0, 0, av); LOAD_B(0, 0, bv);      // 12 reads
        STAGE_B(1, 0, kb1);                      // ph1: B0(Tb)->buf1 (died prev ph8)
        BAR(); MFMA_Q(0, 0, av, bv); BAR();
        LOAD_B(0, 1, bv);                        // 4 reads, keep av=A0
        STAGE_A(0, 0, kna);                      // ph2: A0'->buf0 (A0 died ph1)
        BAR(); MFMA_Q(0, 1, av, bv); BAR();
        LOAD_A(0, 1, av);                        // 8 reads, keep bv=B1
        STAGE_B(0, 1, kna);                      // ph3: B1'->buf0 (B1 died ph2)
        BAR(); MFMA_Q(1, 1, av, bv); BAR();
        LOAD_B(0, 0, bv);                        // 4 reads (B0 again), keep av=A1
        STAGE_A(0, 1, kna);                      // ph4: A1'->buf0 (A1 died ph3)
        VMW6();                                  // 8 buf1(Tb) loads complete
        BAR(); MFMA_Q(1, 0, av, bv); BAR();

        // ---- K-tile b (buf1): same chain ----
        LOAD_A(1, 0, av); LOAD_B(1, 0, bv);
        STAGE_B(0, 0, kna);                      // ph5: B0'->buf0 (B0 died ph4)
        BAR(); MFMA_Q(0, 0, av, bv); BAR();
        LOAD_B(1, 1, bv);
        STAGE_A(1, 0, knb);                      // ph6: A0(Tnb)->buf1 (died ph5)
        BAR(); MFMA_Q(0, 1, av, bv); BAR();
        LOAD_A(1, 1, av);
        STAGE_B(1, 1, knb);                      // ph7: B1(Tnb)->buf1 (died ph6)
        BAR(); MFMA_Q(1, 1, av, bv); BAR();
        LOAD_B(1, 0, bv);
        STAGE_A(1, 1, knb);                      // ph8: A1(Tnb)->buf1 (died ph7)
        VMW6();                                  // 8 buf0(Tna) loads complete
        BAR(); MFMA_Q(1, 0, av, bv); BAR();
    }
#undef STAGE_A
#undef STAGE_B
#undef LOAD_A
#undef LOAD_B
#undef MFMA_Q
#undef BAR
#undef VMW6

    // Epilogue: even combined-cols = kv, odd = gate (adjacent lanes).
    // Lane's 4 acc regs = rows q*4..q*4+3 = one r=4 pooling window.
    const bool is_kv = ((h & 1) == 0);
#pragma unroll
    for (int mi = 0; mi < 8; ++mi) {
        const int mbase = m0 + wm * 128 + mi * 16 + q * 4;
        const int wglob = mbase >> 2;
#pragma unroll
        for (int ni = 0; ni < 4; ++ni) {
            f32x4 kv = acc[mi][ni];
            float g0 = __shfl_xor(kv[0], 1);
            float g1 = __shfl_xor(kv[1], 1);
            float g2 = __shfl_xor(kv[2], 1);
            float g3 = __shfl_xor(kv[3], 1);
            if (is_kv) {
                float s = kv[0] * sigm(g0) + kv[1] * sigm(g1) +
                          kv[2] * sigm(g2) + kv[3] * sigm(g3);
                int n = n0 + wn * 64 + ni * 16 + h;   // even
                int o = n >> 1;
                out_pooled[(size_t)wglob * OD + o] = 0.25f * s + ape_mean[o];
            }
        }
    }
}

// ---- fallback (ws too small for xb): fp32 A + reg staging + XOR swizzle (r3)
__global__ __launch_bounds__(256)
void gemm_fused_f32(const float* __restrict__ Aptr,
                    const unsigned short* __restrict__ Wc,
                    const float* __restrict__ ape_mean,
                    float* __restrict__ out_pooled) {
    __shared__ __align__(16) unsigned short As[128 * BK];
    __shared__ __align__(16) unsigned short Bs[128 * BK];
    const int tid  = threadIdx.x;
    const int lane = tid & 63;
    const int wave = tid >> 6;
    const int wr   = wave >> 1;
    const int wc   = wave & 1;
    const int n0   = blockIdx.x * 128;
    const int m0   = blockIdx.y * 128;
    const int h    = lane & 15;
    const int q    = lane >> 4;

    f32x4 acc[4][4];
    const f32x4 z = {0.f, 0.f, 0.f, 0.f};
#pragma unroll
    for (int i = 0; i < 4; ++i)
#pragma unroll
        for (int jj = 0; jj < 4; ++jj) acc[i][jj] = z;

    for (int kt = 0; kt < D_DIM; kt += BK) {
#pragma unroll
        for (int i = 0; i < 4; ++i) {
            int chunk = tid + i * 256;
            int row = chunk >> 3, c8 = chunk & 7;
            int dst = (row * BK + c8 * 8) ^ ((row & 7) << 3);
            const float4* s = (const float4*)(Aptr + (size_t)(m0 + row) * D_DIM + kt + c8 * 8);
            float4 a = s[0], b = s[1];
            u16x8 o;
            o[0] = f2bf(a.x); o[1] = f2bf(a.y); o[2] = f2bf(a.z); o[3] = f2bf(a.w);
            o[4] = f2bf(b.x); o[5] = f2bf(b.y); o[6] = f2bf(b.z); o[7] = f2bf(b.w);
            *(u16x8*)&As[dst] = o;
        }
#pragma unroll
        for (int i = 0; i < 4; ++i) {
            int chunk = tid + i * 256;
            int row = chunk >> 3, c8 = chunk & 7;
            int dst = (row * BK + c8 * 8) ^ ((row & 7) << 3);
            *(u16x8*)&Bs[dst] =
                *(const u16x8*)(Wc + (size_t)(n0 + row) * D_DIM + kt + c8 * 8);
        }
        __syncthreads();
#pragma unroll
        for (int ks = 0; ks < 2; ++ks) {
            const int kb = ks * 32 + q * 8;
            bf16x8 af[4], bfr[4];
#pragma unroll
            for (int am = 0; am < 4; ++am) {
                int row = wr * 64 + am * 16 + h;
                af[am] = *(const bf16x8*)&As[(row * BK + kb) ^ ((row & 7) << 3)];
            }
#pragma unroll
            for (int bn = 0; bn < 4; ++bn) {
                int row = wc * 64 + bn * 16 + h;
                bfr[bn] = *(const bf16x8*)&Bs[(row * BK + kb) ^ ((row & 7) << 3)];
            }
#pragma unroll
            for (int am = 0; am < 4; ++am)
#pragma unroll
                for (int bn = 0; bn < 4; ++bn)
                    acc[am][bn] = __builtin_amdgcn_mfma_f32_16x16x32_bf16(
                        af[am], bfr[bn], acc[am][bn], 0, 0, 0);
        }
        __syncthreads();
    }
    const bool is_kv = ((h & 1) == 0);
#pragma unroll
    for (int am = 0; am < 4; ++am) {
        const int mbase = m0 + wr * 64 + am * 16 + q * 4;
        const int wglob = mbase >> 2;
#pragma unroll
        for (int bn = 0; bn < 4; ++bn) {
            f32x4 kv = acc[am][bn];
            float g0 = __shfl_xor(kv[0], 1);
            float g1 = __shfl_xor(kv[1], 1);
            float g2 = __shfl_xor(kv[2], 1);
            float g3 = __shfl_xor(kv[3], 1);
            if (is_kv) {
                float s = kv[0] * sigm(g0) + kv[1] * sigm(g1) +
                          kv[2] * sigm(g2) + kv[3] * sigm(g3);
                int n = n0 + wc * 64 + bn * 16 + h;
                int o = n >> 1;
                out_pooled[(size_t)wglob * OD + o] = 0.25f * s + ape_mean[o];
            }
        }
    }
}

// ---- in-place RMSNorm over head_dim=512 per token (8192 tokens)
__global__ void rmsnorm_inplace(float* __restrict__ out, const float* __restrict__ nw) {
    int token = blockIdx.x * 4 + (threadIdx.x >> 6);
    int lane  = threadIdx.x & 63;
    float4* p = (float4*)(out + (size_t)token * 512);
    float4 v0 = p[lane * 2], v1 = p[lane * 2 + 1];
    float ss = v0.x * v0.x + v0.y * v0.y + v0.z * v0.z + v0.w * v0.w +
               v1.x * v1.x + v1.y * v1.y + v1.z * v1.z + v1.w * v1.w;
#pragma unroll
    for (int off = 32; off > 0; off >>= 1) ss += __shfl_xor(ss, off);
    float rs = rsqrtf(ss * (1.0f / 512.0f) + 1e-6f);
    const float4* w4 = (const float4*)nw;
    float4 w0 = w4[lane * 2], w1 = w4[lane * 2 + 1];
    float4 r0, r1;
    r0.x = v0.x * rs * w0.x; r0.y = v0.y * rs * w0.y;
    r0.z = v0.z * rs * w0.z; r0.w = v0.w * rs * w0.w;
    r1.x = v1.x * rs * w1.x; r1.y = v1.y * rs * w1.y;
    r1.z = v1.z * rs * w1.z; r1.w = v1.w * rs * w1.w;
    p[lane * 2]     = r0;
    p[lane * 2 + 1] = r1;
}

extern "C" void kernel_launch(void* const* d_in, const int* in_sizes, int n_in,
                              void* d_out, int out_size, void* d_ws, size_t ws_size,
                              hipStream_t stream) {
    const float* x     = (const float*)d_in[0];
    const float* wkv   = (const float*)d_in[1];
    const float* wgate = (const float*)d_in[2];
    const float* ape   = (const float*)d_in[3];
    const float* normw = (const float*)d_in[4];
    float* out = (float*)d_out;

    unsigned short* Wc  = (unsigned short*)d_ws;
    float* ape_mean     = (float*)((char*)d_ws + (size_t)16 * 1024 * 1024);
    unsigned short* xb  = (unsigned short*)((char*)d_ws + (size_t)16 * 1024 * 1024 + 65536);
    const size_t need_xb = (size_t)16 * 1024 * 1024 + 65536 + (size_t)M_TOT * D_DIM * 2;
    const bool use_xb = (ws_size >= need_xb);

    prep_weights<<<4096, 256, 0, stream>>>(wkv, wgate, Wc);
    prep_ape<<<4, 256, 0, stream>>>(ape, ape_mean);

    if (use_xb) {
        prep_x<<<32768, 256, 0, stream>>>(x, xb);
        (void)hipFuncSetAttribute(
            reinterpret_cast<const void*>(&gemm_fused_8ph),
            hipFuncAttributeMaxDynamicSharedMemorySize, 131072);
        gemm_fused_8ph<<<(M_TOT / BM) * (N_TOT / BN), 512, 131072, stream>>>(
            xb, Wc, ape_mean, out);
    } else {
        gemm_fused_f32<<<dim3(N_TOT / 128, M_TOT / 128), 256, 0, stream>>>(
            x, Wc, ape_mean, out);
    }

    rmsnorm_inplace<<<2048, 256, 0, stream>>>(out, normw);
}

// Round 13
// 307.469 us; speedup vs baseline: 5.5107x; 1.0028x over previous
//
#include <hip/hip_runtime.h>
#include <hip/hip_bf16.h>

// Problem constants (B=4, S=4096, D=4096, r=4, COFF=2, HD=512)
#define D_DIM 4096
#define OD    1024          // COFF*HD combined projection width
#define M_TOT 16384         // B*S
#define N_TOT 2048          // 2*OD (kv/gate interleaved)
#define BM 256
#define BN 256
#define BK 64

#define GLOBAL_AS __attribute__((address_space(1)))
#define LDS_AS    __attribute__((address_space(3)))

typedef __attribute__((ext_vector_type(8))) short          bf16x8;
typedef __attribute__((ext_vector_type(8))) unsigned short u16x8;
typedef __attribute__((ext_vector_type(4))) float          f32x4;

__device__ __forceinline__ unsigned short f2bf(float f) {
    unsigned int u = __float_as_uint(f);
    u = (u + 0x7fffu + ((u >> 16) & 1u)) >> 16;
    return (unsigned short)u;
}

__device__ __forceinline__ float sigm(float x) {
    return 1.0f / (1.0f + __expf(-x));
}

__device__ __forceinline__ void gload16(const void* g, void* l) {
    __builtin_amdgcn_global_load_lds((const GLOBAL_AS void*)g, (LDS_AS void*)l, 16, 0, 0);
}

// ---- prep: interleave wkv/wgate rows into combined bf16 weight [2048][4096]
__global__ void prep_weights(const float* __restrict__ wkv,
                             const float* __restrict__ wgate,
                             unsigned short* __restrict__ Wc) {
    int t  = blockIdx.x * 256 + threadIdx.x;
    int n  = t >> 9;
    int k8 = t & 511;
    const float* src = (n & 1) ? wgate : wkv;
    const float4* s4 = (const float4*)(src + (size_t)(n >> 1) * D_DIM + k8 * 8);
    float4 a = s4[0], b = s4[1];
    u16x8 o;
    o[0] = f2bf(a.x); o[1] = f2bf(a.y); o[2] = f2bf(a.z); o[3] = f2bf(a.w);
    o[4] = f2bf(b.x); o[5] = f2bf(b.y); o[6] = f2bf(b.z); o[7] = f2bf(b.w);
    *(u16x8*)(Wc + (size_t)n * D_DIM + k8 * 8) = o;
}

// ---- prep: x fp32 -> bf16
__global__ void prep_x(const float* __restrict__ x, unsigned short* __restrict__ xb) {
    size_t t = (size_t)blockIdx.x * 256 + threadIdx.x;
    const float4* s = (const float4*)(x + t * 8);
    float4 a = s[0], b = s[1];
    u16x8 o;
    o[0] = f2bf(a.x); o[1] = f2bf(a.y); o[2] = f2bf(a.z); o[3] = f2bf(a.w);
    o[4] = f2bf(b.x); o[5] = f2bf(b.y); o[6] = f2bf(b.z); o[7] = f2bf(b.w);
    *(u16x8*)(xb + t * 8) = o;
}

// ---- prep: ape mean over the 4 window positions
__global__ void prep_ape(const float* __restrict__ ape, float* __restrict__ am) {
    int t = blockIdx.x * 256 + threadIdx.x;
    if (t < OD)
        am[t] = 0.25f * (ape[t] + ape[OD + t] + ape[2 * OD + t] + ape[3 * OD + t]);
}

// =====================================================================
// 256x256 / BK=64 / 8-wave / 8-phase GEMM, r12 schedule (chain
// (0,0)->(0,1)->(1,1)->(1,0), 28 b128/K-tile, uniform 2-gload stages,
// vmcnt(6)@ph4/ph8) + PRECOMPUTED LDS read bases (HK technique):
// swizzled addr decomposes as base[buf][ks] + (frag index)*1024 elems
// (XOR term lives in bits 3-5, frag terms in bits >=10), so the 8
// per-thread bases are loop-invariant and every ds_read_b128 becomes
// base + compile-time immediate offset -> per-phase address VALU ~ 0.
// =====================================================================
extern __shared__ __align__(16) unsigned short smem_u16[];

__global__ __launch_bounds__(512, 2)
void gemm_fused_8ph(const unsigned short* __restrict__ A,
                    const unsigned short* __restrict__ Wc,
                    const float* __restrict__ ape_mean,
                    float* __restrict__ out_pooled) {
    unsigned short* Asb[2] = {smem_u16,               smem_u16 + BM * BK};
    unsigned short* Bsb[2] = {smem_u16 + 2 * BM * BK, smem_u16 + 3 * BM * BK};

    const int tid  = threadIdx.x;
    const int lane = tid & 63;
    const int wave = tid >> 6;          // 8 waves: wm = wave>>2 (2), wn = wave&3 (4)
    const int wm   = wave >> 2;
    const int wn   = wave & 3;
    const int h    = lane & 15;
    const int q    = lane >> 4;

    // XCD partition by m: xcd = bid&7 owns m-tiles [xcd*8, xcd*8+8), all 8 n-tiles.
    const int bid = blockIdx.x;
    const int j   = bid >> 3;
    const int m0  = ((bid & 7) * 8 + (j >> 3)) * BM;
    const int n0  = (j & 7) * BN;

    // staging: pre-swizzled source chunk (rule 21 both-sides; verified r3)
    const int sc8 = (lane & 7) ^ ((lane >> 3) & 7);
    const unsigned short* Ag = A  + (size_t)(m0 + wave * 8 + (lane >> 3)) * D_DIM + sc8 * 8;
    const unsigned short* Bg = Wc + (size_t)(n0 + (wave & 3) * 8 + (lane >> 3)) * D_DIM + sc8 * 8;
    const int bstripe = wave >> 2;      // waves 0-3: stripes {0,2}; 4-7: {1,3}

    // Precomputed LDS read bases (elements). For a fragment row
    // row = W + f*16 + h (W multiple of 64, f = frag idx):
    //   addr = (row*64 + ks*32 + q*8) ^ ((h&7)<<3)
    //        = (W+h)*64 + ((ks*32 + q*8) ^ ((h&7)<<3)) + f*1024.
    const int xorv = (h & 7) << 3;
    const unsigned aoff0 = (unsigned)((wm * 128 + h) * 64);
    const unsigned boff0 = (unsigned)((wn * 64 + h) * 64);
    const unsigned short* aB[2][2];   // [buf][ks]
    const unsigned short* bB[2][2];
#pragma unroll
    for (int b = 0; b < 2; ++b)
#pragma unroll
        for (int ks = 0; ks < 2; ++ks) {
            const unsigned swz = (unsigned)((ks * 32 + q * 8) ^ xorv);
            aB[b][ks] = Asb[b] + aoff0 + swz;
            bB[b][ks] = Bsb[b] + boff0 + swz;
        }

#define STAGE_A(buf, half, kofs)                                                   \
    do {                                                                           \
        gload16(Ag + (size_t)((half) * 64) * D_DIM + (kofs),                       \
                Asb[buf] + ((half) * 64 + wave * 8) * BK);                         \
        gload16(Ag + (size_t)((half) * 64 + 128) * D_DIM + (kofs),                 \
                Asb[buf] + ((half) * 64 + 128 + wave * 8) * BK);                   \
    } while (0)

#define STAGE_B(buf, qb, kofs)                                                     \
    do {                                                                           \
        const int r0_ = (qb) * 32 + bstripe * 64;                                  \
        const int r1_ = (qb) * 32 + (2 + bstripe) * 64;                            \
        gload16(Bg + (size_t)r0_ * D_DIM + (kofs),                                 \
                Bsb[buf] + (r0_ + (wave & 3) * 8) * BK);                           \
        gload16(Bg + (size_t)r1_ * D_DIM + (kofs),                                 \
                Bsb[buf] + (r1_ + (wave & 3) * 8) * BK);                           \
    } while (0)

#define LOAD_A(buf, qa, dst)                                                       \
    do {                                                                           \
        _Pragma("unroll")                                                          \
        for (int mi = 0; mi < 4; ++mi)                                             \
            _Pragma("unroll")                                                      \
            for (int ks = 0; ks < 2; ++ks)                                         \
                dst[mi][ks] = *(const bf16x8*)(aB[buf][ks] +                       \
                              ((qa) * 4 + mi) * 1024);                             \
    } while (0)

#define LOAD_B(buf, qb, dst)                                                       \
    do {                                                                           \
        _Pragma("unroll")                                                          \
        for (int ni = 0; ni < 2; ++ni)                                             \
            _Pragma("unroll")                                                      \
            for (int ks = 0; ks < 2; ++ks)                                         \
                dst[ni][ks] = *(const bf16x8*)(bB[buf][ks] +                       \
                              ((qb) * 2 + ni) * 1024);                             \
    } while (0)

#define MFMA_Q(qa, qb, asrc, bsrc)                                                 \
    do {                                                                           \
        __builtin_amdgcn_s_setprio(1);                                             \
        _Pragma("unroll")                                                          \
        for (int mi = 0; mi < 4; ++mi)                                             \
            _Pragma("unroll")                                                      \
            for (int ni = 0; ni < 2; ++ni)                                         \
                _Pragma("unroll")                                                  \
                for (int ks = 0; ks < 2; ++ks)                                     \
                    acc[(qa) * 4 + mi][(qb) * 2 + ni] =                            \
                        __builtin_amdgcn_mfma_f32_16x16x32_bf16(                   \
                            asrc[mi][ks], bsrc[ni][ks],                            \
                            acc[(qa) * 4 + mi][(qb) * 2 + ni], 0, 0, 0);           \
        __builtin_amdgcn_s_setprio(0);                                             \
    } while (0)

#define BAR() __builtin_amdgcn_s_barrier()
#define VMW6() asm volatile("s_waitcnt vmcnt(6)" ::: "memory")

    f32x4 acc[8][4];
    const f32x4 z = {0.f, 0.f, 0.f, 0.f};
#pragma unroll
    for (int i = 0; i < 8; ++i)
#pragma unroll
        for (int jj = 0; jj < 4; ++jj) acc[i][jj] = z;

    // prologue: buf0 <- T0 full (8 loads), buf1 <- T1 {A0,B1,A1} (6 loads).
    // vmcnt(6): buf0's 8 complete, buf1's 6 outstanding = steady invariant.
    STAGE_A(0, 0, 0); STAGE_A(0, 1, 0); STAGE_B(0, 0, 0); STAGE_B(0, 1, 0);
    STAGE_A(1, 0, 64); STAGE_B(1, 1, 64); STAGE_A(1, 1, 64);
    VMW6();
    BAR();

    for (int kt2 = 0; kt2 < D_DIM; kt2 += 2 * BK) {
        const int kb1 = kt2 + BK;                // buf1 tile this iter (<= 4032)
        const int kna = (kt2 + 2 * BK) & 4095;   // next buf0 tile (wraps: dead)
        const int knb = (kt2 + 3 * BK) & 4095;   // next buf1 tile (wraps: dead)
        bf16x8 av[4][2], bv[2][2];

        // ---- K-tile a (buf0): (0,0) -> (0,1) -> (1,1) -> (1,0) ----
        LOAD_A(0, 0, av); LOAD_B(0, 0, bv);      // 12 reads
        STAGE_B(1, 0, kb1);                      // ph1: B0(Tb)->buf1 (died prev ph8)
        BAR(); MFMA_Q(0, 0, av, bv); BAR();
        LOAD_B(0, 1, bv);                        // 4 reads, keep av=A0
        STAGE_A(0, 0, kna);                      // ph2: A0'->buf0 (A0 died ph1)
        BAR(); MFMA_Q(0, 1, av, bv); BAR();
        LOAD_A(0, 1, av);                        // 8 reads, keep bv=B1
        STAGE_B(0, 1, kna);                      // ph3: B1'->buf0 (B1 died ph2)
        BAR(); MFMA_Q(1, 1, av, bv); BAR();
        LOAD_B(0, 0, bv);                        // 4 reads (B0 again), keep av=A1
        STAGE_A(0, 1, kna);                      // ph4: A1'->buf0 (A1 died ph3)
        VMW6();                                  // 8 buf1(Tb) loads complete
        BAR(); MFMA_Q(1, 0, av, bv); BAR();

        // ---- K-tile b (buf1): same chain ----
        LOAD_A(1, 0, av); LOAD_B(1, 0, bv);
        STAGE_B(0, 0, kna);                      // ph5: B0'->buf0 (B0 died ph4)
        BAR(); MFMA_Q(0, 0, av, bv); BAR();
        LOAD_B(1, 1, bv);
        STAGE_A(1, 0, knb);                      // ph6: A0(Tnb)->buf1 (died ph5)
        BAR(); MFMA_Q(0, 1, av, bv); BAR();
        LOAD_A(1, 1, av);
        STAGE_B(1, 1, knb);                      // ph7: B1(Tnb)->buf1 (died ph6)
        BAR(); MFMA_Q(1, 1, av, bv); BAR();
        LOAD_B(1, 0, bv);
        STAGE_A(1, 1, knb);                      // ph8: A1(Tnb)->buf1 (died ph7)
        VMW6();                                  // 8 buf0(Tna) loads complete
        BAR(); MFMA_Q(1, 0, av, bv); BAR();
    }
#undef STAGE_A
#undef STAGE_B
#undef LOAD_A
#undef LOAD_B
#undef MFMA_Q
#undef BAR
#undef VMW6

    // Epilogue: even combined-cols = kv, odd = gate (adjacent lanes).
    // Lane's 4 acc regs = rows q*4..q*4+3 = one r=4 pooling window.
    const bool is_kv = ((h & 1) == 0);
#pragma unroll
    for (int mi = 0; mi < 8; ++mi) {
        const int mbase = m0 + wm * 128 + mi * 16 + q * 4;
        const int wglob = mbase >> 2;
#pragma unroll
        for (int ni = 0; ni < 4; ++ni) {
            f32x4 kv = acc[mi][ni];
            float g0 = __shfl_xor(kv[0], 1);
            float g1 = __shfl_xor(kv[1], 1);
            float g2 = __shfl_xor(kv[2], 1);
            float g3 = __shfl_xor(kv[3], 1);
            if (is_kv) {
                float s = kv[0] * sigm(g0) + kv[1] * sigm(g1) +
                          kv[2] * sigm(g2) + kv[3] * sigm(g3);
                int n = n0 + wn * 64 + ni * 16 + h;   // even
                int o = n >> 1;
                out_pooled[(size_t)wglob * OD + o] = 0.25f * s + ape_mean[o];
            }
        }
    }
}

// ---- fallback (ws too small for xb): fp32 A + reg staging + XOR swizzle (r3)
__global__ __launch_bounds__(256)
void gemm_fused_f32(const float* __restrict__ Aptr,
                    const unsigned short* __restrict__ Wc,
                    const float* __restrict__ ape_mean,
                    float* __restrict__ out_pooled) {
    __shared__ __align__(16) unsigned short As[128 * BK];
    __shared__ __align__(16) unsigned short Bs[128 * BK];
    const int tid  = threadIdx.x;
    const int lane = tid & 63;
    const int wave = tid >> 6;
    const int wr   = wave >> 1;
    const int wc   = wave & 1;
    const int n0   = blockIdx.x * 128;
    const int m0   = blockIdx.y * 128;
    const int h    = lane & 15;
    const int q    = lane >> 4;

    f32x4 acc[4][4];
    const f32x4 z = {0.f, 0.f, 0.f, 0.f};
#pragma unroll
    for (int i = 0; i < 4; ++i)
#pragma unroll
        for (int jj = 0; jj < 4; ++jj) acc[i][jj] = z;

    for (int kt = 0; kt < D_DIM; kt += BK) {
#pragma unroll
        for (int i = 0; i < 4; ++i) {
            int chunk = tid + i * 256;
            int row = chunk >> 3, c8 = chunk & 7;
            int dst = (row * BK + c8 * 8) ^ ((row & 7) << 3);
            const float4* s = (const float4*)(Aptr + (size_t)(m0 + row) * D_DIM + kt + c8 * 8);
            float4 a = s[0], b = s[1];
            u16x8 o;
            o[0] = f2bf(a.x); o[1] = f2bf(a.y); o[2] = f2bf(a.z); o[3] = f2bf(a.w);
            o[4] = f2bf(b.x); o[5] = f2bf(b.y); o[6] = f2bf(b.z); o[7] = f2bf(b.w);
            *(u16x8*)&As[dst] = o;
        }
#pragma unroll
        for (int i = 0; i < 4; ++i) {
            int chunk = tid + i * 256;
            int row = chunk >> 3, c8 = chunk & 7;
            int dst = (row * BK + c8 * 8) ^ ((row & 7) << 3);
            *(u16x8*)&Bs[dst] =
                *(const u16x8*)(Wc + (size_t)(n0 + row) * D_DIM + kt + c8 * 8);
        }
        __syncthreads();
#pragma unroll
        for (int ks = 0; ks < 2; ++ks) {
            const int kb = ks * 32 + q * 8;
            bf16x8 af[4], bfr[4];
#pragma unroll
            for (int am = 0; am < 4; ++am) {
                int row = wr * 64 + am * 16 + h;
                af[am] = *(const bf16x8*)&As[(row * BK + kb) ^ ((row & 7) << 3)];
            }
#pragma unroll
            for (int bn = 0; bn < 4; ++bn) {
                int row = wc * 64 + bn * 16 + h;
                bfr[bn] = *(const bf16x8*)&Bs[(row * BK + kb) ^ ((row & 7) << 3)];
            }
#pragma unroll
            for (int am = 0; am < 4; ++am)
#pragma unroll
                for (int bn = 0; bn < 4; ++bn)
                    acc[am][bn] = __builtin_amdgcn_mfma_f32_16x16x32_bf16(
                        af[am], bfr[bn], acc[am][bn], 0, 0, 0);
        }
        __syncthreads();
    }
    const bool is_kv = ((h & 1) == 0);
#pragma unroll
    for (int am = 0; am < 4; ++am) {
        const int mbase = m0 + wr * 64 + am * 16 + q * 4;
        const int wglob = mbase >> 2;
#pragma unroll
        for (int bn = 0; bn < 4; ++bn) {
            f32x4 kv = acc[am][bn];
            float g0 = __shfl_xor(kv[0], 1);
            float g1 = __shfl_xor(kv[1], 1);
            float g2 = __shfl_xor(kv[2], 1);
            float g3 = __shfl_xor(kv[3], 1);
            if (is_kv) {
                float s = kv[0] * sigm(g0) + kv[1] * sigm(g1) +
                          kv[2] * sigm(g2) + kv[3] * sigm(g3);
                int n = n0 + wc * 64 + bn * 16 + h;
                int o = n >> 1;
                out_pooled[(size_t)wglob * OD + o] = 0.25f * s + ape_mean[o];
            }
        }
    }
}

// ---- in-place RMSNorm over head_dim=512 per token (8192 tokens)
__global__ void rmsnorm_inplace(float* __restrict__ out, const float* __restrict__ nw) {
    int token = blockIdx.x * 4 + (threadIdx.x >> 6);
    int lane  = threadIdx.x & 63;
    float4* p = (float4*)(out + (size_t)token * 512);
    float4 v0 = p[lane * 2], v1 = p[lane * 2 + 1];
    float ss = v0.x * v0.x + v0.y * v0.y + v0.z * v0.z + v0.w * v0.w +
               v1.x * v1.x + v1.y * v1.y + v1.z * v1.z + v1.w * v1.w;
#pragma unroll
    for (int off = 32; off > 0; off >>= 1) ss += __shfl_xor(ss, off);
    float rs = rsqrtf(ss * (1.0f / 512.0f) + 1e-6f);
    const float4* w4 = (const float4*)nw;
    float4 w0 = w4[lane * 2], w1 = w4[lane * 2 + 1];
    float4 r0, r1;
    r0.x = v0.x * rs * w0.x; r0.y = v0.y * rs * w0.y;
    r0.z = v0.z * rs * w0.z; r0.w = v0.w * rs * w0.w;
    r1.x = v1.x * rs * w1.x; r1.y = v1.y * rs * w1.y;
    r1.z = v1.z * rs * w1.z; r1.w = v1.w * rs * w1.w;
    p[lane * 2]     = r0;
    p[lane * 2 + 1] = r1;
}

extern "C" void kernel_launch(void* const* d_in, const int* in_sizes, int n_in,
                              void* d_out, int out_size, void* d_ws, size_t ws_size,
                              hipStream_t stream) {
    const float* x     = (const float*)d_in[0];
    const float* wkv   = (const float*)d_in[1];
    const float* wgate = (const float*)d_in[2];
    const float* ape   = (const float*)d_in[3];
    const float* normw = (const float*)d_in[4];
    float* out = (float*)d_out;

    unsigned short* Wc  = (unsigned short*)d_ws;
    float* ape_mean     = (float*)((char*)d_ws + (size_t)16 * 1024 * 1024);
    unsigned short* xb  = (unsigned short*)((char*)d_ws + (size_t)16 * 1024 * 1024 + 65536);
    const size_t need_xb = (size_t)16 * 1024 * 1024 + 65536 + (size_t)M_TOT * D_DIM * 2;
    const bool use_xb = (ws_size >= need_xb);

    prep_weights<<<4096, 256, 0, stream>>>(wkv, wgate, Wc);
    prep_ape<<<4, 256, 0, stream>>>(ape, ape_mean);

    if (use_xb) {
        prep_x<<<32768, 256, 0, stream>>>(x, xb);
        (void)hipFuncSetAttribute(
            reinterpret_cast<const void*>(&gemm_fused_8ph),
            hipFuncAttributeMaxDynamicSharedMemorySize, 131072);
        gemm_fused_8ph<<<(M_TOT / BM) * (N_TOT / BN), 512, 131072, stream>>>(
            xb, Wc, ape_mean, out);
    } else {
        gemm_fused_f32<<<dim3(N_TOT / 128, M_TOT / 128), 256, 0, stream>>>(
            x, Wc, ape_mean, out);
    }

    rmsnorm_inplace<<<2048, 256, 0, stream>>>(out, normw);
}